// Round 2
// baseline (23615.887 us; speedup 1.0000x reference)
//
#include <hip/hip_runtime.h>
#include <hip/hip_bf16.h>

#define NLAYER 8
#define HDIM   768
#define EDIM   1536
#define NST    16
#define LSEQ   2048
#define BATCH  2
#define BLTOK  (BATCH*LSEQ)   /* 4096 tokens */

__device__ __forceinline__ float sigm(float x){ return 1.0f/(1.0f+__expf(-x)); }

// ---------------------------------------------------------------------------
// Generic tiled GEMM: C[M,N] (fp32) = A[M,K] (fp32) @ W[K,N] (fp32) + bias
// EPI bit0: SiLU on result; bit1: accumulate into C (C += v) instead of store.
// M is always 4096 (grid.y = 64, 64 rows per tile). N may be non-multiple of 64.
// ---------------------------------------------------------------------------
template<int EPI>
__global__ __launch_bounds__(256) void gemm_k(
    const float* __restrict__ A, const float* __restrict__ W,
    const float* __restrict__ bias, float* __restrict__ C,
    int N, int K)
{
  __shared__ float As[16][64];   // k-major A tile
  __shared__ float Bs[16][64];
  const int bm = blockIdx.y << 6;
  const int bn = blockIdx.x << 6;
  const int tid = threadIdx.x;
  const int tx = tid & 15, ty = tid >> 4;
  const int am = tid >> 2, ak = (tid & 3) << 2;   // A-tile load coords
  const int bk = tid >> 4, bn4 = (tid & 15) << 2; // B-tile load coords
  float acc[4][4] = {};

  for (int k0 = 0; k0 < K; k0 += 16){
    // load A tile (64 rows x 16 k), transpose into k-major LDS
    float4 av = *reinterpret_cast<const float4*>(A + (size_t)(bm+am)*K + k0 + ak);
    As[ak+0][am]=av.x; As[ak+1][am]=av.y; As[ak+2][am]=av.z; As[ak+3][am]=av.w;
    // load B tile (16 k x 64 n)
    const float* wrow = W + (size_t)(k0+bk)*N + bn + bn4;
    float b0,b1,b2,b3;
    if (bn + bn4 + 3 < N){
      float4 rv = *reinterpret_cast<const float4*>(wrow);
      b0=rv.x; b1=rv.y; b2=rv.z; b3=rv.w;
    } else {
      int c0 = bn + bn4;
      b0 = (c0+0<N)?wrow[0]:0.f;
      b1 = (c0+1<N)?wrow[1]:0.f;
      b2 = (c0+2<N)?wrow[2]:0.f;
      b3 = (c0+3<N)?wrow[3]:0.f;
    }
    Bs[bk][bn4+0]=b0; Bs[bk][bn4+1]=b1; Bs[bk][bn4+2]=b2; Bs[bk][bn4+3]=b3;
    __syncthreads();
    #pragma unroll
    for (int kk = 0; kk < 16; kk++){
      float4 a4 = *reinterpret_cast<const float4*>(&As[kk][ty<<2]);
      float4 b4 = *reinterpret_cast<const float4*>(&Bs[kk][tx<<2]);
      float aa[4] = {a4.x,a4.y,a4.z,a4.w};
      float bb[4] = {b4.x,b4.y,b4.z,b4.w};
      #pragma unroll
      for (int i=0;i<4;i++)
        #pragma unroll
        for (int j=0;j<4;j++) acc[i][j] += aa[i]*bb[j];
    }
    __syncthreads();
  }

  #pragma unroll
  for (int i=0;i<4;i++){
    int row = bm + (ty<<2) + i;
    #pragma unroll
    for (int j=0;j<4;j++){
      int col = bn + (tx<<2) + j;
      if (col < N){
        float v = acc[i][j];
        if (bias) v += bias[col];
        if (EPI & 1) v *= sigm(v);   // SiLU
        size_t o = (size_t)row*N + col;
        if (EPI & 2) C[o] += v; else C[o] = v;
      }
    }
  }
}

// ---------------------------------------------------------------------------
// hs = tok_emb[ids] + pos_emb[l]
// ---------------------------------------------------------------------------
__global__ __launch_bounds__(256) void embed_k(
    const int* __restrict__ ids, const float* __restrict__ tok,
    const float* __restrict__ pos, float* __restrict__ HS)
{
  int idx = blockIdx.x*256 + threadIdx.x;         // over BLTOK*HDIM
  int h = idx % HDIM; int t = idx / HDIM;
  int lpos = t % LSEQ;
  int id = ids[t];
  HS[idx] = tok[id*HDIM + h] + pos[lpos*HDIM + h];
}

// ---------------------------------------------------------------------------
// LayerNorm over H=768, one block per token; O fp32
// ---------------------------------------------------------------------------
__global__ __launch_bounds__(256) void ln_k(
    const float* __restrict__ X, const float* __restrict__ w,
    const float* __restrict__ b, float* __restrict__ O)
{
  int t = blockIdx.x;
  const float* x = X + (size_t)t*HDIM;
  float s=0.f, s2=0.f;
  for (int i=threadIdx.x; i<HDIM; i+=256){ float v=x[i]; s+=v; s2+=v*v; }
  #pragma unroll
  for (int off=32; off; off>>=1){ s += __shfl_down(s,off,64); s2 += __shfl_down(s2,off,64); }
  __shared__ float rs[4], rs2[4], mv[2];
  int lane = threadIdx.x & 63, wv = threadIdx.x >> 6;
  if (!lane){ rs[wv]=s; rs2[wv]=s2; }
  __syncthreads();
  if (!threadIdx.x){
    float a = rs[0]+rs[1]+rs[2]+rs[3];
    float c = rs2[0]+rs2[1]+rs2[2]+rs2[3];
    float m = a/HDIM;
    mv[0]=m; mv[1]=rsqrtf(c/HDIM - m*m + 1e-5f);
  }
  __syncthreads();
  float m = mv[0], r = mv[1];
  for (int i=threadIdx.x; i<HDIM; i+=256)
    O[(size_t)t*HDIM+i] = (x[i]-m)*r*w[i] + b[i];
}

// ---------------------------------------------------------------------------
// causal depthwise conv (K=4) over xm = PROJ[:,:, :E], then SiLU -> U
// ---------------------------------------------------------------------------
__global__ __launch_bounds__(256) void conv_silu_k(
    const float* __restrict__ PROJ, const float* __restrict__ cw,
    const float* __restrict__ cb, float* __restrict__ U)
{
  int idx = blockIdx.x*256 + threadIdx.x;   // over BLTOK*EDIM
  int e = idx % EDIM; int t = idx / EDIM;
  int l = t % LSEQ; int tb = t - l;         // batch base token
  float acc = cb[e];
  #pragma unroll
  for (int j=0;j<4;j++){
    int tt = l + j - 3;
    if (tt >= 0) acc += PROJ[(size_t)(tb+tt)*(2*EDIM) + e] * cw[e*4+j];
  }
  U[idx] = acc * sigm(acc);
}

// ---------------------------------------------------------------------------
// dt = softplus(dbc[:, :4] @ dt_w + dt_b), stored into PROJ[:, :, :E] (xm dead)
// ---------------------------------------------------------------------------
__global__ __launch_bounds__(256) void dt_k(
    const float* __restrict__ DBC, const float* __restrict__ dtw,
    const float* __restrict__ dtb, float* __restrict__ DT)
{
  int idx = blockIdx.x*256 + threadIdx.x;   // over BLTOK*EDIM
  int e = idx % EDIM; int t = idx / EDIM;
  const float* d = DBC + (size_t)t*36;
  float v = dtb[e];
  #pragma unroll
  for (int r=0;r<4;r++) v += d[r]*dtw[r*EDIM+e];
  v = (v > 20.f) ? v : log1pf(__expf(v));
  DT[(size_t)t*(2*EDIM) + e] = v;
}

// ---------------------------------------------------------------------------
// selective scan: one thread per (b,e) channel; h[16] in regs.
// dt read from PROJ[:, :, :E]; gate from PROJ[:, :, E:]; fused sigmoid-gate+D.
// ---------------------------------------------------------------------------
__global__ __launch_bounds__(256) void scan_k(
    const float* __restrict__ U, const float* __restrict__ PROJ,
    const float* __restrict__ DBC, const float* __restrict__ Alog,
    const float* __restrict__ Dp, float* __restrict__ Y)
{
  int idx = blockIdx.x*256 + threadIdx.x;   // over BATCH*EDIM
  int e = idx % EDIM; int b = idx / EDIM;
  float a[NST], h[NST];
  #pragma unroll
  for (int n=0;n<NST;n++){ a[n] = -__expf(Alog[e*NST+n]); h[n]=0.f; }
  float dcf = Dp[e];
  for (int t=0;t<LSEQ;t++){
    size_t tok = (size_t)b*LSEQ + t;
    float dt = PROJ[tok*(2*EDIM) + e];
    float u  = U[tok*EDIM + e];
    const float* bc = DBC + tok*36;
    float du = dt*u;
    float y = 0.f;
    #pragma unroll
    for (int n=0;n<NST;n++){
      h[n] = h[n]*__expf(dt*a[n]) + du*bc[4+n];
      y += h[n]*bc[20+n];
    }
    float g = PROJ[tok*(2*EDIM) + EDIM + e];
    Y[tok*EDIM + e] = (y + u*dcf) * sigm(g);
  }
}

// HS += ACC / 6   (hs = hs + 0.5*acc/C, C=3)
__global__ __launch_bounds__(256) void addscale_k(
    float* __restrict__ HS, const float* __restrict__ ACC)
{
  int i = blockIdx.x*256 + threadIdx.x;
  HS[i] += ACC[i] * (0.5f/3.0f);
}

// Final LN -> f32 output
__global__ __launch_bounds__(256) void lnout_k(
    const float* __restrict__ X, const float* __restrict__ w,
    const float* __restrict__ b, float* __restrict__ O)
{
  int t = blockIdx.x;
  const float* x = X + (size_t)t*HDIM;
  float s=0.f, s2=0.f;
  for (int i=threadIdx.x; i<HDIM; i+=256){ float v=x[i]; s+=v; s2+=v*v; }
  #pragma unroll
  for (int off=32; off; off>>=1){ s += __shfl_down(s,off,64); s2 += __shfl_down(s2,off,64); }
  __shared__ float rs[4], rs2[4], mv[2];
  int lane = threadIdx.x & 63, wv = threadIdx.x >> 6;
  if (!lane){ rs[wv]=s; rs2[wv]=s2; }
  __syncthreads();
  if (!threadIdx.x){
    float a = rs[0]+rs[1]+rs[2]+rs[3];
    float c = rs2[0]+rs2[1]+rs2[2]+rs2[3];
    float m = a/HDIM;
    mv[0]=m; mv[1]=rsqrtf(c/HDIM - m*m + 1e-5f);
  }
  __syncthreads();
  float m = mv[0], r = mv[1];
  for (int i=threadIdx.x; i<HDIM; i+=256)
    O[(size_t)t*HDIM+i] = (x[i]-m)*r*w[i] + b[i];
}

// ---------------------------------------------------------------------------
extern "C" void kernel_launch(void* const* d_in, const int* in_sizes, int n_in,
                              void* d_out, int out_size, void* d_ws, size_t ws_size,
                              hipStream_t stream)
{
  const int*   ids      = (const int*)d_in[0];
  const float* tok_emb  = (const float*)d_in[1];
  const float* pos_emb  = (const float*)d_in[2];
  const float* ln_w     = (const float*)d_in[3];
  const float* ln_b     = (const float*)d_in[4];
  const float* in_w     = (const float*)d_in[5];
  const float* in_b     = (const float*)d_in[6];
  const float* conv_w   = (const float*)d_in[7];
  const float* conv_b   = (const float*)d_in[8];
  const float* xproj_w  = (const float*)d_in[9];
  const float* dt_w     = (const float*)d_in[10];
  const float* dt_b     = (const float*)d_in[11];
  const float* A_log    = (const float*)d_in[12];
  const float* Dp       = (const float*)d_in[13];
  const float* out_w    = (const float*)d_in[14];
  const float* out_b    = (const float*)d_in[15];
  const float* frac_w   = (const float*)d_in[16];
  const float* frac_b   = (const float*)d_in[17];
  const float* fln_w    = (const float*)d_in[18];
  const float* fln_b    = (const float*)d_in[19];

  // fp32 workspace layout (~120.6 MiB)
  float* HS   = (float*)d_ws;                       // 4096*768
  float* XB   = HS   + (size_t)BLTOK*HDIM;          // 4096*768
  float* PROJ = XB   + (size_t)BLTOK*HDIM;          // 4096*3072  (xm|gate, later dt|gate)
  float* Ubuf = PROJ + (size_t)BLTOK*2*EDIM;        // 4096*1536
  float* Ybuf = Ubuf + (size_t)BLTOK*EDIM;          // 4096*1536
  float* DBC  = Ybuf + (size_t)BLTOK*EDIM;          // 4096*36
  // aliases (U/Y dead after out-projection)
  float* FR1  = Ubuf;
  float* FR2  = Ubuf + (size_t)BLTOK*HDIM;
  float* ACCb = Ybuf;

  embed_k<<<(BLTOK*HDIM)/256, 256, 0, stream>>>(ids, tok_emb, pos_emb, HS);

  for (int l = 0; l < NLAYER; l++){
    ln_k<<<BLTOK, 256, 0, stream>>>(HS, ln_w + l*HDIM, ln_b + l*HDIM, XB);

    // proj = LN(hs) @ in_w + in_b   [4096 x 768 x 3072]
    gemm_k<0><<<dim3((2*EDIM)/64, 64), 256, 0, stream>>>(
        XB, in_w + (size_t)l*HDIM*2*EDIM, in_b + l*2*EDIM, PROJ, 2*EDIM, HDIM);

    // u = silu(causal_dwconv(xm))
    conv_silu_k<<<(BLTOK*EDIM)/256, 256, 0, stream>>>(
        PROJ, conv_w + l*EDIM*4, conv_b + l*EDIM, Ubuf);

    // dbc = u @ xproj_w   [4096 x 1536 x 36]
    gemm_k<0><<<dim3(1, 64), 256, 0, stream>>>(
        Ubuf, xproj_w + (size_t)l*EDIM*36, nullptr, DBC, 36, EDIM);

    // dt = softplus(dbc[:, :4] @ dt_w + dt_b) -> stored into PROJ[:, :E]
    dt_k<<<(BLTOK*EDIM)/256, 256, 0, stream>>>(
        DBC, dt_w + l*4*EDIM, dt_b + l*EDIM, PROJ);

    // y = sigmoid(gate) * (selective_scan(u, dt, B, C, A) + u*D)
    scan_k<<<(BATCH*EDIM)/256, 256, 0, stream>>>(
        Ubuf, PROJ, DBC, A_log + (size_t)l*EDIM*NST, Dp + l*EDIM, Ybuf);

    // hs += y @ out_w + out_b   [4096 x 1536 x 768]
    gemm_k<2><<<dim3(HDIM/64, 64), 256, 0, stream>>>(
        Ybuf, out_w + (size_t)l*EDIM*HDIM, out_b + l*HDIM, HS, HDIM, EDIM);

    // fractal: acc = sum_i silu^3-chain(hs); hs += acc/6
    for (int i = 0; i < 3; i++){
      const float* fw = frac_w + (size_t)(l*3+i)*HDIM*HDIM;
      const float* fb = frac_b + (size_t)(l*3+i)*HDIM;
      gemm_k<1><<<dim3(HDIM/64, 64), 256, 0, stream>>>(HS,  fw, fb, FR1, HDIM, HDIM);
      gemm_k<1><<<dim3(HDIM/64, 64), 256, 0, stream>>>(FR1, fw, fb, FR2, HDIM, HDIM);
      if (i == 0)
        gemm_k<1><<<dim3(HDIM/64, 64), 256, 0, stream>>>(FR2, fw, fb, ACCb, HDIM, HDIM);
      else
        gemm_k<3><<<dim3(HDIM/64, 64), 256, 0, stream>>>(FR2, fw, fb, ACCb, HDIM, HDIM);
    }
    addscale_k<<<(BLTOK*HDIM)/256, 256, 0, stream>>>(HS, ACCb);
  }

  lnout_k<<<BLTOK, 256, 0, stream>>>(HS, fln_w, fln_b, (float*)d_out);
}

// Round 3
// 13319.096 us; speedup vs baseline: 1.7731x; 1.7731x over previous
//
#include <hip/hip_runtime.h>
#include <hip/hip_bf16.h>

#define NLAYER 8
#define HDIM   768
#define EDIM   1536
#define NST    16
#define LSEQ   2048
#define BATCH  2
#define BLTOK  (BATCH*LSEQ)   /* 4096 tokens */

__device__ __forceinline__ float sigm(float x){ return 1.0f/(1.0f+__expf(-x)); }

// ---------------------------------------------------------------------------
// Generic tiled GEMM: C[M,N] (fp32) = A[M,K] (fp32) @ W[K,N] (fp32) + bias
// EPI bit0: SiLU on result; bit1: accumulate into C (C += v) instead of store.
// M is always 4096 (grid.y = 64, 64 rows per tile). N may be non-multiple of 64.
// ---------------------------------------------------------------------------
template<int EPI>
__global__ __launch_bounds__(256) void gemm_k(
    const float* __restrict__ A, const float* __restrict__ W,
    const float* __restrict__ bias, float* __restrict__ C,
    int N, int K)
{
  __shared__ float As[16][64];   // k-major A tile
  __shared__ float Bs[16][64];
  const int bm = blockIdx.y << 6;
  const int bn = blockIdx.x << 6;
  const int tid = threadIdx.x;
  const int tx = tid & 15, ty = tid >> 4;
  const int am = tid >> 2, ak = (tid & 3) << 2;   // A-tile load coords
  const int bk = tid >> 4, bn4 = (tid & 15) << 2; // B-tile load coords
  float acc[4][4] = {};

  for (int k0 = 0; k0 < K; k0 += 16){
    // load A tile (64 rows x 16 k), transpose into k-major LDS
    float4 av = *reinterpret_cast<const float4*>(A + (size_t)(bm+am)*K + k0 + ak);
    As[ak+0][am]=av.x; As[ak+1][am]=av.y; As[ak+2][am]=av.z; As[ak+3][am]=av.w;
    // load B tile (16 k x 64 n)
    const float* wrow = W + (size_t)(k0+bk)*N + bn + bn4;
    float b0,b1,b2,b3;
    if (bn + bn4 + 3 < N){
      float4 rv = *reinterpret_cast<const float4*>(wrow);
      b0=rv.x; b1=rv.y; b2=rv.z; b3=rv.w;
    } else {
      int c0 = bn + bn4;
      b0 = (c0+0<N)?wrow[0]:0.f;
      b1 = (c0+1<N)?wrow[1]:0.f;
      b2 = (c0+2<N)?wrow[2]:0.f;
      b3 = (c0+3<N)?wrow[3]:0.f;
    }
    Bs[bk][bn4+0]=b0; Bs[bk][bn4+1]=b1; Bs[bk][bn4+2]=b2; Bs[bk][bn4+3]=b3;
    __syncthreads();
    #pragma unroll
    for (int kk = 0; kk < 16; kk++){
      float4 a4 = *reinterpret_cast<const float4*>(&As[kk][ty<<2]);
      float4 b4 = *reinterpret_cast<const float4*>(&Bs[kk][tx<<2]);
      float aa[4] = {a4.x,a4.y,a4.z,a4.w};
      float bb[4] = {b4.x,b4.y,b4.z,b4.w};
      #pragma unroll
      for (int i=0;i<4;i++)
        #pragma unroll
        for (int j=0;j<4;j++) acc[i][j] += aa[i]*bb[j];
    }
    __syncthreads();
  }

  #pragma unroll
  for (int i=0;i<4;i++){
    int row = bm + (ty<<2) + i;
    #pragma unroll
    for (int j=0;j<4;j++){
      int col = bn + (tx<<2) + j;
      if (col < N){
        float v = acc[i][j];
        if (bias) v += bias[col];
        if (EPI & 1) v *= sigm(v);   // SiLU
        size_t o = (size_t)row*N + col;
        if (EPI & 2) C[o] += v; else C[o] = v;
      }
    }
  }
}

// ---------------------------------------------------------------------------
// hs = tok_emb[ids] + pos_emb[l]
// ---------------------------------------------------------------------------
__global__ __launch_bounds__(256) void embed_k(
    const int* __restrict__ ids, const float* __restrict__ tok,
    const float* __restrict__ pos, float* __restrict__ HS)
{
  int idx = blockIdx.x*256 + threadIdx.x;         // over BLTOK*HDIM
  int h = idx % HDIM; int t = idx / HDIM;
  int lpos = t % LSEQ;
  int id = ids[t];
  HS[idx] = tok[id*HDIM + h] + pos[lpos*HDIM + h];
}

// ---------------------------------------------------------------------------
// LayerNorm over H=768, one block per token; O fp32
// ---------------------------------------------------------------------------
__global__ __launch_bounds__(256) void ln_k(
    const float* __restrict__ X, const float* __restrict__ w,
    const float* __restrict__ b, float* __restrict__ O)
{
  int t = blockIdx.x;
  const float* x = X + (size_t)t*HDIM;
  float s=0.f, s2=0.f;
  for (int i=threadIdx.x; i<HDIM; i+=256){ float v=x[i]; s+=v; s2+=v*v; }
  #pragma unroll
  for (int off=32; off; off>>=1){ s += __shfl_down(s,off,64); s2 += __shfl_down(s2,off,64); }
  __shared__ float rs[4], rs2[4], mv[2];
  int lane = threadIdx.x & 63, wv = threadIdx.x >> 6;
  if (!lane){ rs[wv]=s; rs2[wv]=s2; }
  __syncthreads();
  if (!threadIdx.x){
    float a = rs[0]+rs[1]+rs[2]+rs[3];
    float c = rs2[0]+rs2[1]+rs2[2]+rs2[3];
    float m = a/HDIM;
    mv[0]=m; mv[1]=rsqrtf(c/HDIM - m*m + 1e-5f);
  }
  __syncthreads();
  float m = mv[0], r = mv[1];
  for (int i=threadIdx.x; i<HDIM; i+=256)
    O[(size_t)t*HDIM+i] = (x[i]-m)*r*w[i] + b[i];
}

// ---------------------------------------------------------------------------
// causal depthwise conv (K=4) over xm = PROJ[:,:, :E], then SiLU -> U
// ---------------------------------------------------------------------------
__global__ __launch_bounds__(256) void conv_silu_k(
    const float* __restrict__ PROJ, const float* __restrict__ cw,
    const float* __restrict__ cb, float* __restrict__ U)
{
  int idx = blockIdx.x*256 + threadIdx.x;   // over BLTOK*EDIM
  int e = idx % EDIM; int t = idx / EDIM;
  int l = t % LSEQ; int tb = t - l;         // batch base token
  float acc = cb[e];
  #pragma unroll
  for (int j=0;j<4;j++){
    int tt = l + j - 3;
    if (tt >= 0) acc += PROJ[(size_t)(tb+tt)*(2*EDIM) + e] * cw[e*4+j];
  }
  U[idx] = acc * sigm(acc);
}

// ---------------------------------------------------------------------------
// dt = softplus(dbc[:, :4] @ dt_w + dt_b), stored into PROJ[:, :, :E] (xm dead)
// ---------------------------------------------------------------------------
__global__ __launch_bounds__(256) void dt_k(
    const float* __restrict__ DBC, const float* __restrict__ dtw,
    const float* __restrict__ dtb, float* __restrict__ DT)
{
  int idx = blockIdx.x*256 + threadIdx.x;   // over BLTOK*EDIM
  int e = idx % EDIM; int t = idx / EDIM;
  const float* d = DBC + (size_t)t*36;
  float v = dtb[e];
  #pragma unroll
  for (int r=0;r<4;r++) v += d[r]*dtw[r*EDIM+e];
  v = (v > 20.f) ? v : log1pf(__expf(v));
  DT[(size_t)t*(2*EDIM) + e] = v;
}

// ---------------------------------------------------------------------------
// Chunked parallel selective scan.
// One block per (b,e) channel. 256 threads = 16 states (lane bits 0-3)
// x 16 time-chunks of 128 steps (bits 4-7).
// The recurrence h_t = dA_t*h_{t-1} + x_t is linear in h, so each chunk is
// an affine map h_out = P*h_in + S. Pass 1 computes (P,S) per chunk; a
// 16-step serial combine in LDS yields each chunk's h_in; pass 2 recomputes
// outputs with the true h_in, shfl_xor-reducing y = sum_n h*C_n across the
// 16 state-lanes (in-wave: state bits are lane bits 0-3).
// ---------------------------------------------------------------------------
__global__ __launch_bounds__(256) void scan2_k(
    const float* __restrict__ U, const float* __restrict__ PROJ,
    const float* __restrict__ DBC, const float* __restrict__ Alog,
    const float* __restrict__ Dp, float* __restrict__ Y)
{
  const int CH = LSEQ/16;            // 128 steps per chunk
  int ch = blockIdx.x;               // (b,e) channel
  int e = ch % EDIM, b = ch / EDIM;
  int tid = threadIdx.x;
  int n = tid & 15, j = tid >> 4;    // state, chunk

  float a = -__expf(Alog[e*NST + n]);
  size_t base = (size_t)b*LSEQ;
  int t0 = j*CH;

  __shared__ float Pl[16][17], Sl[16][17], Hin[16][17];  // [chunk][state]

  // pass 1: chunk-local affine map (P, S) starting from h=0
  float P = 1.f, h = 0.f;
  for (int t = t0; t < t0+CH; t++){
    size_t tok = base + t;
    float dt = PROJ[tok*(2*EDIM) + e];
    float u  = U[tok*EDIM + e];
    float Bn = DBC[tok*36 + 4 + n];
    float dA = __expf(dt*a);
    P *= dA;
    h = h*dA + dt*u*Bn;
  }
  Pl[j][n] = P; Sl[j][n] = h;
  __syncthreads();

  // combine: serial over 16 chunks, parallel over 16 states
  if (tid < 16){
    float hin = 0.f;
    #pragma unroll
    for (int jj = 0; jj < 16; jj++){
      Hin[jj][tid] = hin;
      hin = Pl[jj][tid]*hin + Sl[jj][tid];
    }
  }
  __syncthreads();

  // pass 2: recompute with true h_in, emit gated outputs
  h = Hin[j][n];
  float dcf = Dp[e];
  for (int t = t0; t < t0+CH; t++){
    size_t tok = base + t;
    float dt = PROJ[tok*(2*EDIM) + e];
    float u  = U[tok*EDIM + e];
    float Bn = DBC[tok*36 + 4 + n];
    float Cn = DBC[tok*36 + 20 + n];
    float dA = __expf(dt*a);
    h = h*dA + dt*u*Bn;
    float v = h*Cn;
    v += __shfl_xor(v, 1, 64);
    v += __shfl_xor(v, 2, 64);
    v += __shfl_xor(v, 4, 64);
    v += __shfl_xor(v, 8, 64);
    if (n == 0){
      float g = PROJ[tok*(2*EDIM) + EDIM + e];
      Y[tok*EDIM + e] = (v + u*dcf)*sigm(g);
    }
  }
}

// HS += ACC / 6   (hs = hs + 0.5*acc/C, C=3)
__global__ __launch_bounds__(256) void addscale_k(
    float* __restrict__ HS, const float* __restrict__ ACC)
{
  int i = blockIdx.x*256 + threadIdx.x;
  HS[i] += ACC[i] * (0.5f/3.0f);
}

// Final LN -> f32 output
__global__ __launch_bounds__(256) void lnout_k(
    const float* __restrict__ X, const float* __restrict__ w,
    const float* __restrict__ b, float* __restrict__ O)
{
  int t = blockIdx.x;
  const float* x = X + (size_t)t*HDIM;
  float s=0.f, s2=0.f;
  for (int i=threadIdx.x; i<HDIM; i+=256){ float v=x[i]; s+=v; s2+=v*v; }
  #pragma unroll
  for (int off=32; off; off>>=1){ s += __shfl_down(s,off,64); s2 += __shfl_down(s2,off,64); }
  __shared__ float rs[4], rs2[4], mv[2];
  int lane = threadIdx.x & 63, wv = threadIdx.x >> 6;
  if (!lane){ rs[wv]=s; rs2[wv]=s2; }
  __syncthreads();
  if (!threadIdx.x){
    float a = rs[0]+rs[1]+rs[2]+rs[3];
    float c = rs2[0]+rs2[1]+rs2[2]+rs2[3];
    float m = a/HDIM;
    mv[0]=m; mv[1]=rsqrtf(c/HDIM - m*m + 1e-5f);
  }
  __syncthreads();
  float m = mv[0], r = mv[1];
  for (int i=threadIdx.x; i<HDIM; i+=256)
    O[(size_t)t*HDIM+i] = (x[i]-m)*r*w[i] + b[i];
}

// ---------------------------------------------------------------------------
extern "C" void kernel_launch(void* const* d_in, const int* in_sizes, int n_in,
                              void* d_out, int out_size, void* d_ws, size_t ws_size,
                              hipStream_t stream)
{
  const int*   ids      = (const int*)d_in[0];
  const float* tok_emb  = (const float*)d_in[1];
  const float* pos_emb  = (const float*)d_in[2];
  const float* ln_w     = (const float*)d_in[3];
  const float* ln_b     = (const float*)d_in[4];
  const float* in_w     = (const float*)d_in[5];
  const float* in_b     = (const float*)d_in[6];
  const float* conv_w   = (const float*)d_in[7];
  const float* conv_b   = (const float*)d_in[8];
  const float* xproj_w  = (const float*)d_in[9];
  const float* dt_w     = (const float*)d_in[10];
  const float* dt_b     = (const float*)d_in[11];
  const float* A_log    = (const float*)d_in[12];
  const float* Dp       = (const float*)d_in[13];
  const float* out_w    = (const float*)d_in[14];
  const float* out_b    = (const float*)d_in[15];
  const float* frac_w   = (const float*)d_in[16];
  const float* frac_b   = (const float*)d_in[17];
  const float* fln_w    = (const float*)d_in[18];
  const float* fln_b    = (const float*)d_in[19];

  // fp32 workspace layout (~120.6 MiB)
  float* HS   = (float*)d_ws;                       // 4096*768
  float* XB   = HS   + (size_t)BLTOK*HDIM;          // 4096*768
  float* PROJ = XB   + (size_t)BLTOK*HDIM;          // 4096*3072  (xm|gate, later dt|gate)
  float* Ubuf = PROJ + (size_t)BLTOK*2*EDIM;        // 4096*1536
  float* Ybuf = Ubuf + (size_t)BLTOK*EDIM;          // 4096*1536
  float* DBC  = Ybuf + (size_t)BLTOK*EDIM;          // 4096*36
  // aliases (U/Y dead after out-projection)
  float* FR1  = Ubuf;
  float* FR2  = Ubuf + (size_t)BLTOK*HDIM;
  float* ACCb = Ybuf;

  embed_k<<<(BLTOK*HDIM)/256, 256, 0, stream>>>(ids, tok_emb, pos_emb, HS);

  for (int l = 0; l < NLAYER; l++){
    ln_k<<<BLTOK, 256, 0, stream>>>(HS, ln_w + l*HDIM, ln_b + l*HDIM, XB);

    // proj = LN(hs) @ in_w + in_b   [4096 x 768 x 3072]
    gemm_k<0><<<dim3((2*EDIM)/64, 64), 256, 0, stream>>>(
        XB, in_w + (size_t)l*HDIM*2*EDIM, in_b + l*2*EDIM, PROJ, 2*EDIM, HDIM);

    // u = silu(causal_dwconv(xm))
    conv_silu_k<<<(BLTOK*EDIM)/256, 256, 0, stream>>>(
        PROJ, conv_w + l*EDIM*4, conv_b + l*EDIM, Ubuf);

    // dbc = u @ xproj_w   [4096 x 1536 x 36]
    gemm_k<0><<<dim3(1, 64), 256, 0, stream>>>(
        Ubuf, xproj_w + (size_t)l*EDIM*36, nullptr, DBC, 36, EDIM);

    // dt = softplus(dbc[:, :4] @ dt_w + dt_b) -> stored into PROJ[:, :E]
    dt_k<<<(BLTOK*EDIM)/256, 256, 0, stream>>>(
        DBC, dt_w + l*4*EDIM, dt_b + l*EDIM, PROJ);

    // y = sigmoid(gate) * (selective_scan(u, dt, B, C, A) + u*D)
    scan2_k<<<BATCH*EDIM, 256, 0, stream>>>(
        Ubuf, PROJ, DBC, A_log + (size_t)l*EDIM*NST, Dp + l*EDIM, Ybuf);

    // hs += y @ out_w + out_b   [4096 x 1536 x 768]
    gemm_k<2><<<dim3(HDIM/64, 64), 256, 0, stream>>>(
        Ybuf, out_w + (size_t)l*EDIM*HDIM, out_b + l*HDIM, HS, HDIM, EDIM);

    // fractal: acc = sum_i silu^3-chain(hs); hs += acc/6
    for (int i = 0; i < 3; i++){
      const float* fw = frac_w + (size_t)(l*3+i)*HDIM*HDIM;
      const float* fb = frac_b + (size_t)(l*3+i)*HDIM;
      gemm_k<1><<<dim3(HDIM/64, 64), 256, 0, stream>>>(HS,  fw, fb, FR1, HDIM, HDIM);
      gemm_k<1><<<dim3(HDIM/64, 64), 256, 0, stream>>>(FR1, fw, fb, FR2, HDIM, HDIM);
      if (i == 0)
        gemm_k<1><<<dim3(HDIM/64, 64), 256, 0, stream>>>(FR2, fw, fb, ACCb, HDIM, HDIM);
      else
        gemm_k<3><<<dim3(HDIM/64, 64), 256, 0, stream>>>(FR2, fw, fb, ACCb, HDIM, HDIM);
    }
    addscale_k<<<(BLTOK*HDIM)/256, 256, 0, stream>>>(HS, ACCb);
  }

  lnout_k<<<BLTOK, 256, 0, stream>>>(HS, fln_w, fln_b, (float*)d_out);
}

// Round 4
// 9455.331 us; speedup vs baseline: 2.4976x; 1.4086x over previous
//
#include <hip/hip_runtime.h>
#include <hip/hip_bf16.h>

#define NLAYER 8
#define HDIM   768
#define EDIM   1536
#define NST    16
#define LSEQ   2048
#define BATCH  2
#define BLTOK  (BATCH*LSEQ)   /* 4096 tokens */

typedef short  short8  __attribute__((ext_vector_type(8)));
typedef float  f32x4   __attribute__((ext_vector_type(4)));

__device__ __forceinline__ float sigm(float x){ return 1.0f/(1.0f+__expf(-x)); }

__device__ __forceinline__ unsigned short bf16_rne(float x){
  unsigned u = __float_as_uint(x);
  return (unsigned short)((u + 0x7fffu + ((u>>16)&1u)) >> 16);
}
__device__ __forceinline__ float bf16_f(unsigned short h){
  return __uint_as_float(((unsigned)h)<<16);
}

// ---------------------------------------------------------------------------
// MFMA bf16x3 GEMM: C[M,N](f32) = A[M,K](f32) @ W[K,N](f32) + bias
// A,W split on the fly into hi+lo bf16; D += Ah*Bh + Ah*Bl + Al*Bh.
// Tile 128x128, BK=32, 4 waves/block, per-wave 4x4 of 16x16x32 MFMA.
// Requires M%128==0, N%128==0, K%32==0.
// EPI bit0: SiLU; bit1: accumulate (C += v).
// ---------------------------------------------------------------------------
template<int EPI>
__global__ __launch_bounds__(256) void mgemm_k(
    const float* __restrict__ A, const float* __restrict__ W,
    const float* __restrict__ bias, float* __restrict__ C,
    int N, int K)
{
  // rows padded to 40 bf16 (80 B): 20-bank stride -> conflict-free b128 reads
  __shared__ unsigned short AsH[128*40], AsL[128*40], BsH[128*40], BsL[128*40];
  const int tid  = threadIdx.x;
  const int m0 = blockIdx.y<<7, n0 = blockIdx.x<<7;
  const int wave = tid>>6, lane = tid&63;
  const int r = lane&15, q = lane>>4;
  const int wm = (wave&1)<<6, wn = (wave>>1)<<6;
  const int sr = tid & 127;        // staging row (m or n)
  const int kc = (tid>>7)<<4;      // staging k chunk (0 or 16)

  f32x4 acc[4][4];
  #pragma unroll
  for (int i=0;i<4;i++)
    #pragma unroll
    for (int j=0;j<4;j++)
      #pragma unroll
      for (int t=0;t<4;t++) acc[i][j][t]=0.f;

  for (int k0 = 0; k0 < K; k0 += 32){
    // ---- stage A tile: rows m0..m0+127, k0..k0+31 (k-contig per thread)
    {
      const float* ap = A + (size_t)(m0+sr)*K + k0 + kc;
      float f[16];
      *(float4*)&f[0]  = *(const float4*)(ap+0);
      *(float4*)&f[4]  = *(const float4*)(ap+4);
      *(float4*)&f[8]  = *(const float4*)(ap+8);
      *(float4*)&f[12] = *(const float4*)(ap+12);
      unsigned short hh[16], ll[16];
      #pragma unroll
      for (int t=0;t<16;t++){
        unsigned short h = bf16_rne(f[t]);
        hh[t]=h; ll[t]=bf16_rne(f[t]-bf16_f(h));
      }
      int o = sr*40 + kc;
      *(short8*)&AsH[o]   = *(short8*)&hh[0];
      *(short8*)&AsH[o+8] = *(short8*)&hh[8];
      *(short8*)&AsL[o]   = *(short8*)&ll[0];
      *(short8*)&AsL[o+8] = *(short8*)&ll[8];
    }
    // ---- stage B tile transposed: Bs[n][k], n0..n0+127, k0..k0+31
    {
      const float* wp = W + (size_t)(k0+kc)*N + n0 + sr;
      float f[16];
      #pragma unroll
      for (int t=0;t<16;t++) f[t] = wp[(size_t)t*N];
      unsigned short hh[16], ll[16];
      #pragma unroll
      for (int t=0;t<16;t++){
        unsigned short h = bf16_rne(f[t]);
        hh[t]=h; ll[t]=bf16_rne(f[t]-bf16_f(h));
      }
      int o = sr*40 + kc;
      *(short8*)&BsH[o]   = *(short8*)&hh[0];
      *(short8*)&BsH[o+8] = *(short8*)&hh[8];
      *(short8*)&BsL[o]   = *(short8*)&ll[0];
      *(short8*)&BsL[o+8] = *(short8*)&ll[8];
    }
    __syncthreads();

    short8 aH[4], aL[4], bH[4], bL[4];
    #pragma unroll
    for (int i=0;i<4;i++){
      int o = (wm + 16*i + r)*40 + q*8;
      aH[i] = *(const short8*)&AsH[o];
      aL[i] = *(const short8*)&AsL[o];
    }
    #pragma unroll
    for (int j=0;j<4;j++){
      int o = (wn + 16*j + r)*40 + q*8;
      bH[j] = *(const short8*)&BsH[o];
      bL[j] = *(const short8*)&BsL[o];
    }
    #pragma unroll
    for (int i=0;i<4;i++)
      #pragma unroll
      for (int j=0;j<4;j++){
        acc[i][j] = __builtin_amdgcn_mfma_f32_16x16x32_bf16(aH[i], bH[j], acc[i][j], 0,0,0);
        acc[i][j] = __builtin_amdgcn_mfma_f32_16x16x32_bf16(aH[i], bL[j], acc[i][j], 0,0,0);
        acc[i][j] = __builtin_amdgcn_mfma_f32_16x16x32_bf16(aL[i], bH[j], acc[i][j], 0,0,0);
      }
    __syncthreads();
  }

  // epilogue: D col = lane&15 (n), row = 4q+reg (m)
  #pragma unroll
  for (int j=0;j<4;j++){
    int n_out = n0 + wn + 16*j + r;
    float bv = bias ? bias[n_out] : 0.f;
    #pragma unroll
    for (int i=0;i<4;i++){
      #pragma unroll
      for (int reg=0;reg<4;reg++){
        int m_out = m0 + wm + 16*i + 4*q + reg;
        float v = acc[i][j][reg] + bv;
        if (EPI & 1) v *= sigm(v);
        size_t o = (size_t)m_out*N + n_out;
        if (EPI & 2) C[o] += v; else C[o] = v;
      }
    }
  }
}

// ---------------------------------------------------------------------------
// Old fp32 tiled GEMM (kept for xproj, N=36)
// ---------------------------------------------------------------------------
template<int EPI>
__global__ __launch_bounds__(256) void gemm_k(
    const float* __restrict__ A, const float* __restrict__ W,
    const float* __restrict__ bias, float* __restrict__ C,
    int N, int K)
{
  __shared__ float As[16][64];
  __shared__ float Bs[16][64];
  const int bm = blockIdx.y << 6;
  const int bn = blockIdx.x << 6;
  const int tid = threadIdx.x;
  const int tx = tid & 15, ty = tid >> 4;
  const int am = tid >> 2, ak = (tid & 3) << 2;
  const int bk = tid >> 4, bn4 = (tid & 15) << 2;
  float acc[4][4] = {};

  for (int k0 = 0; k0 < K; k0 += 16){
    float4 av = *reinterpret_cast<const float4*>(A + (size_t)(bm+am)*K + k0 + ak);
    As[ak+0][am]=av.x; As[ak+1][am]=av.y; As[ak+2][am]=av.z; As[ak+3][am]=av.w;
    const float* wrow = W + (size_t)(k0+bk)*N + bn + bn4;
    float b0,b1,b2,b3;
    if (bn + bn4 + 3 < N){
      float4 rv = *reinterpret_cast<const float4*>(wrow);
      b0=rv.x; b1=rv.y; b2=rv.z; b3=rv.w;
    } else {
      int c0 = bn + bn4;
      b0 = (c0+0<N)?wrow[0]:0.f;
      b1 = (c0+1<N)?wrow[1]:0.f;
      b2 = (c0+2<N)?wrow[2]:0.f;
      b3 = (c0+3<N)?wrow[3]:0.f;
    }
    Bs[bk][bn4+0]=b0; Bs[bk][bn4+1]=b1; Bs[bk][bn4+2]=b2; Bs[bk][bn4+3]=b3;
    __syncthreads();
    #pragma unroll
    for (int kk = 0; kk < 16; kk++){
      float4 a4 = *reinterpret_cast<const float4*>(&As[kk][ty<<2]);
      float4 b4 = *reinterpret_cast<const float4*>(&Bs[kk][tx<<2]);
      float aa[4] = {a4.x,a4.y,a4.z,a4.w};
      float bb[4] = {b4.x,b4.y,b4.z,b4.w};
      #pragma unroll
      for (int i=0;i<4;i++)
        #pragma unroll
        for (int j=0;j<4;j++) acc[i][j] += aa[i]*bb[j];
    }
    __syncthreads();
  }

  #pragma unroll
  for (int i=0;i<4;i++){
    int row = bm + (ty<<2) + i;
    #pragma unroll
    for (int j=0;j<4;j++){
      int col = bn + (tx<<2) + j;
      if (col < N){
        float v = acc[i][j];
        if (bias) v += bias[col];
        if (EPI & 1) v *= sigm(v);
        size_t o = (size_t)row*N + col;
        if (EPI & 2) C[o] += v; else C[o] = v;
      }
    }
  }
}

// ---------------------------------------------------------------------------
__global__ __launch_bounds__(256) void embed_k(
    const int* __restrict__ ids, const float* __restrict__ tok,
    const float* __restrict__ pos, float* __restrict__ HS)
{
  int idx = blockIdx.x*256 + threadIdx.x;
  int h = idx % HDIM; int t = idx / HDIM;
  int lpos = t % LSEQ;
  int id = ids[t];
  HS[idx] = tok[id*HDIM + h] + pos[lpos*HDIM + h];
}

// ---------------------------------------------------------------------------
__global__ __launch_bounds__(256) void ln_k(
    const float* __restrict__ X, const float* __restrict__ w,
    const float* __restrict__ b, float* __restrict__ O)
{
  int t = blockIdx.x;
  const float* x = X + (size_t)t*HDIM;
  float s=0.f, s2=0.f;
  for (int i=threadIdx.x; i<HDIM; i+=256){ float v=x[i]; s+=v; s2+=v*v; }
  #pragma unroll
  for (int off=32; off; off>>=1){ s += __shfl_down(s,off,64); s2 += __shfl_down(s2,off,64); }
  __shared__ float rs[4], rs2[4], mv[2];
  int lane = threadIdx.x & 63, wv = threadIdx.x >> 6;
  if (!lane){ rs[wv]=s; rs2[wv]=s2; }
  __syncthreads();
  if (!threadIdx.x){
    float a = rs[0]+rs[1]+rs[2]+rs[3];
    float c = rs2[0]+rs2[1]+rs2[2]+rs2[3];
    float m = a/HDIM;
    mv[0]=m; mv[1]=rsqrtf(c/HDIM - m*m + 1e-5f);
  }
  __syncthreads();
  float m = mv[0], r = mv[1];
  for (int i=threadIdx.x; i<HDIM; i+=256)
    O[(size_t)t*HDIM+i] = (x[i]-m)*r*w[i] + b[i];
}

// ---------------------------------------------------------------------------
__global__ __launch_bounds__(256) void conv_silu_k(
    const float* __restrict__ PROJ, const float* __restrict__ cw,
    const float* __restrict__ cb, float* __restrict__ U)
{
  int idx = blockIdx.x*256 + threadIdx.x;
  int e = idx % EDIM; int t = idx / EDIM;
  int l = t % LSEQ; int tb = t - l;
  float acc = cb[e];
  #pragma unroll
  for (int j=0;j<4;j++){
    int tt = l + j - 3;
    if (tt >= 0) acc += PROJ[(size_t)(tb+tt)*(2*EDIM) + e] * cw[e*4+j];
  }
  U[idx] = acc * sigm(acc);
}

// ---------------------------------------------------------------------------
__global__ __launch_bounds__(256) void dt_k(
    const float* __restrict__ DBC, const float* __restrict__ dtw,
    const float* __restrict__ dtb, float* __restrict__ DT)
{
  int idx = blockIdx.x*256 + threadIdx.x;
  int e = idx % EDIM; int t = idx / EDIM;
  const float* d = DBC + (size_t)t*36;
  float v = dtb[e];
  #pragma unroll
  for (int r=0;r<4;r++) v += d[r]*dtw[r*EDIM+e];
  v = (v > 20.f) ? v : log1pf(__expf(v));
  DT[(size_t)t*(2*EDIM) + e] = v;
}

// ---------------------------------------------------------------------------
// Chunked parallel selective scan (see round 3).
// ---------------------------------------------------------------------------
__global__ __launch_bounds__(256) void scan2_k(
    const float* __restrict__ U, const float* __restrict__ PROJ,
    const float* __restrict__ DBC, const float* __restrict__ Alog,
    const float* __restrict__ Dp, float* __restrict__ Y)
{
  const int CH = LSEQ/16;
  int ch = blockIdx.x;
  int e = ch % EDIM, b = ch / EDIM;
  int tid = threadIdx.x;
  int n = tid & 15, j = tid >> 4;

  float a = -__expf(Alog[e*NST + n]);
  size_t base = (size_t)b*LSEQ;
  int t0 = j*CH;

  __shared__ float Pl[16][17], Sl[16][17], Hin[16][17];

  float P = 1.f, h = 0.f;
  for (int t = t0; t < t0+CH; t++){
    size_t tok = base + t;
    float dt = PROJ[tok*(2*EDIM) + e];
    float u  = U[tok*EDIM + e];
    float Bn = DBC[tok*36 + 4 + n];
    float dA = __expf(dt*a);
    P *= dA;
    h = h*dA + dt*u*Bn;
  }
  Pl[j][n] = P; Sl[j][n] = h;
  __syncthreads();

  if (tid < 16){
    float hin = 0.f;
    #pragma unroll
    for (int jj = 0; jj < 16; jj++){
      Hin[jj][tid] = hin;
      hin = Pl[jj][tid]*hin + Sl[jj][tid];
    }
  }
  __syncthreads();

  h = Hin[j][n];
  float dcf = Dp[e];
  for (int t = t0; t < t0+CH; t++){
    size_t tok = base + t;
    float dt = PROJ[tok*(2*EDIM) + e];
    float u  = U[tok*EDIM + e];
    float Bn = DBC[tok*36 + 4 + n];
    float Cn = DBC[tok*36 + 20 + n];
    float dA = __expf(dt*a);
    h = h*dA + dt*u*Bn;
    float v = h*Cn;
    v += __shfl_xor(v, 1, 64);
    v += __shfl_xor(v, 2, 64);
    v += __shfl_xor(v, 4, 64);
    v += __shfl_xor(v, 8, 64);
    if (n == 0){
      float g = PROJ[tok*(2*EDIM) + EDIM + e];
      Y[tok*EDIM + e] = (v + u*dcf)*sigm(g);
    }
  }
}

__global__ __launch_bounds__(256) void addscale_k(
    float* __restrict__ HS, const float* __restrict__ ACC)
{
  int i = blockIdx.x*256 + threadIdx.x;
  HS[i] += ACC[i] * (0.5f/3.0f);
}

__global__ __launch_bounds__(256) void lnout_k(
    const float* __restrict__ X, const float* __restrict__ w,
    const float* __restrict__ b, float* __restrict__ O)
{
  int t = blockIdx.x;
  const float* x = X + (size_t)t*HDIM;
  float s=0.f, s2=0.f;
  for (int i=threadIdx.x; i<HDIM; i+=256){ float v=x[i]; s+=v; s2+=v*v; }
  #pragma unroll
  for (int off=32; off; off>>=1){ s += __shfl_down(s,off,64); s2 += __shfl_down(s2,off,64); }
  __shared__ float rs[4], rs2[4], mv[2];
  int lane = threadIdx.x & 63, wv = threadIdx.x >> 6;
  if (!lane){ rs[wv]=s; rs2[wv]=s2; }
  __syncthreads();
  if (!threadIdx.x){
    float a = rs[0]+rs[1]+rs[2]+rs[3];
    float c = rs2[0]+rs2[1]+rs2[2]+rs2[3];
    float m = a/HDIM;
    mv[0]=m; mv[1]=rsqrtf(c/HDIM - m*m + 1e-5f);
  }
  __syncthreads();
  float m = mv[0], r = mv[1];
  for (int i=threadIdx.x; i<HDIM; i+=256)
    O[(size_t)t*HDIM+i] = (x[i]-m)*r*w[i] + b[i];
}

// ---------------------------------------------------------------------------
extern "C" void kernel_launch(void* const* d_in, const int* in_sizes, int n_in,
                              void* d_out, int out_size, void* d_ws, size_t ws_size,
                              hipStream_t stream)
{
  const int*   ids      = (const int*)d_in[0];
  const float* tok_emb  = (const float*)d_in[1];
  const float* pos_emb  = (const float*)d_in[2];
  const float* ln_w     = (const float*)d_in[3];
  const float* ln_b     = (const float*)d_in[4];
  const float* in_w     = (const float*)d_in[5];
  const float* in_b     = (const float*)d_in[6];
  const float* conv_w   = (const float*)d_in[7];
  const float* conv_b   = (const float*)d_in[8];
  const float* xproj_w  = (const float*)d_in[9];
  const float* dt_w     = (const float*)d_in[10];
  const float* dt_b     = (const float*)d_in[11];
  const float* A_log    = (const float*)d_in[12];
  const float* Dp       = (const float*)d_in[13];
  const float* out_w    = (const float*)d_in[14];
  const float* out_b    = (const float*)d_in[15];
  const float* frac_w   = (const float*)d_in[16];
  const float* frac_b   = (const float*)d_in[17];
  const float* fln_w    = (const float*)d_in[18];
  const float* fln_b    = (const float*)d_in[19];

  float* HS   = (float*)d_ws;
  float* XB   = HS   + (size_t)BLTOK*HDIM;
  float* PROJ = XB   + (size_t)BLTOK*HDIM;
  float* Ubuf = PROJ + (size_t)BLTOK*2*EDIM;
  float* Ybuf = Ubuf + (size_t)BLTOK*EDIM;
  float* DBC  = Ybuf + (size_t)BLTOK*EDIM;
  float* FR1  = Ubuf;
  float* FR2  = Ubuf + (size_t)BLTOK*HDIM;
  float* ACCb = Ybuf;

  embed_k<<<(BLTOK*HDIM)/256, 256, 0, stream>>>(ids, tok_emb, pos_emb, HS);

  for (int l = 0; l < NLAYER; l++){
    ln_k<<<BLTOK, 256, 0, stream>>>(HS, ln_w + l*HDIM, ln_b + l*HDIM, XB);

    // proj = LN(hs) @ in_w + in_b   [4096 x 768 x 3072]
    mgemm_k<0><<<dim3((2*EDIM)/128, BLTOK/128), 256, 0, stream>>>(
        XB, in_w + (size_t)l*HDIM*2*EDIM, in_b + l*2*EDIM, PROJ, 2*EDIM, HDIM);

    conv_silu_k<<<(BLTOK*EDIM)/256, 256, 0, stream>>>(
        PROJ, conv_w + l*EDIM*4, conv_b + l*EDIM, Ubuf);

    // dbc = u @ xproj_w   [4096 x 1536 x 36]  (tiny N -> fp32 path)
    gemm_k<0><<<dim3(1, 64), 256, 0, stream>>>(
        Ubuf, xproj_w + (size_t)l*EDIM*36, nullptr, DBC, 36, EDIM);

    dt_k<<<(BLTOK*EDIM)/256, 256, 0, stream>>>(
        DBC, dt_w + l*4*EDIM, dt_b + l*EDIM, PROJ);

    scan2_k<<<BATCH*EDIM, 256, 0, stream>>>(
        Ubuf, PROJ, DBC, A_log + (size_t)l*EDIM*NST, Dp + l*EDIM, Ybuf);

    // hs += y @ out_w + out_b   [4096 x 1536 x 768]
    mgemm_k<2><<<dim3(HDIM/128, BLTOK/128), 256, 0, stream>>>(
        Ybuf, out_w + (size_t)l*EDIM*HDIM, out_b + l*HDIM, HS, HDIM, EDIM);

    // fractal
    for (int i = 0; i < 3; i++){
      const float* fw = frac_w + (size_t)(l*3+i)*HDIM*HDIM;
      const float* fb = frac_b + (size_t)(l*3+i)*HDIM;
      mgemm_k<1><<<dim3(HDIM/128, BLTOK/128), 256, 0, stream>>>(HS,  fw, fb, FR1, HDIM, HDIM);
      mgemm_k<1><<<dim3(HDIM/128, BLTOK/128), 256, 0, stream>>>(FR1, fw, fb, FR2, HDIM, HDIM);
      if (i == 0)
        mgemm_k<1><<<dim3(HDIM/128, BLTOK/128), 256, 0, stream>>>(FR2, fw, fb, ACCb, HDIM, HDIM);
      else
        mgemm_k<3><<<dim3(HDIM/128, BLTOK/128), 256, 0, stream>>>(FR2, fw, fb, ACCb, HDIM, HDIM);
    }
    addscale_k<<<(BLTOK*HDIM)/256, 256, 0, stream>>>(HS, ACCb);
  }

  lnout_k<<<BLTOK, 256, 0, stream>>>(HS, fln_w, fln_b, (float*)d_out);
}

// Round 5
// 8220.323 us; speedup vs baseline: 2.8729x; 1.1502x over previous
//
#include <hip/hip_runtime.h>
#include <hip/hip_bf16.h>

#define NLAYER 8
#define HDIM   768
#define EDIM   1536
#define NST    16
#define LSEQ   2048
#define BATCH  2
#define BLTOK  (BATCH*LSEQ)   /* 4096 tokens */

typedef unsigned short u16;
typedef short  short8  __attribute__((ext_vector_type(8)));
typedef float  f32x4   __attribute__((ext_vector_type(4)));

__device__ __forceinline__ float sigm(float x){ return 1.0f/(1.0f+__expf(-x)); }

__device__ __forceinline__ u16 bf16_rne(float x){
  unsigned u = __float_as_uint(x);
  return (u16)((u + 0x7fffu + ((u>>16)&1u)) >> 16);
}
__device__ __forceinline__ float bf16_f(u16 h){
  return __uint_as_float(((unsigned)h)<<16);
}

// ---------------------------------------------------------------------------
// Weight prep: W[K][Nsrc] fp32  ->  H/L[Ndst][K] bf16 hi/lo (transposed).
// Pads n in [Nsrc,Ndst) with zeros. grid=(Ndst/32, K/32, nz), block=256.
// ---------------------------------------------------------------------------
__global__ __launch_bounds__(256) void wprep_k(
    const float* __restrict__ W, u16* __restrict__ H, u16* __restrict__ L,
    int Nsrc, int Ndst, int K)
{
  __shared__ float T[32][33];
  int z = blockIdx.z;
  W += (size_t)z*K*Nsrc; H += (size_t)z*Ndst*K; L += (size_t)z*Ndst*K;
  int n0 = blockIdx.x*32, k0 = blockIdx.y*32;
  int tx = threadIdx.x&31, ty = threadIdx.x>>5;
  #pragma unroll
  for (int r=0;r<4;r++){
    int kk = ty+8*r, col = n0+tx;
    T[kk][tx] = (col<Nsrc) ? W[(size_t)(k0+kk)*Nsrc+col] : 0.f;
  }
  __syncthreads();
  #pragma unroll
  for (int r=0;r<4;r++){
    int nn = ty+8*r, n = n0+nn, k = k0+tx;
    if (n<Ndst){
      float f = T[tx][nn];
      u16 h = bf16_rne(f);
      H[(size_t)n*K+k] = h;
      L[(size_t)n*K+k] = bf16_rne(f - bf16_f(h));
    }
  }
}

// ---------------------------------------------------------------------------
// MFMA bf16x3 GEMM with pre-split weights.
// C[M,N](f32) = A[M,K](f32) @ W + bias;  W given as WH/WL[N][K] bf16.
// Tile 128x128, BK=32, 4 waves, per-wave 4x4 of 16x16x32 MFMA.
// EPI bit0: SiLU; bit1: accumulate. blockIdx.z strides for batched (fractal).
// ---------------------------------------------------------------------------
template<int EPI>
__global__ __launch_bounds__(256) void mgemm2_k(
    const float* __restrict__ A, const u16* __restrict__ WH,
    const u16* __restrict__ WL, const float* __restrict__ bias,
    float* __restrict__ C, int N, int K,
    size_t zA, size_t zW, size_t zB, size_t zC)
{
  const int z = blockIdx.z;
  A += (size_t)z*zA; WH += (size_t)z*zW; WL += (size_t)z*zW;
  C += (size_t)z*zC;
  if (bias) bias += (size_t)z*zB;

  __shared__ u16 AsH[128*40], AsL[128*40], BsH[128*40], BsL[128*40];
  const int tid  = threadIdx.x;
  const int m0 = blockIdx.y<<7, n0 = blockIdx.x<<7;
  const int wave = tid>>6, lane = tid&63;
  const int r = lane&15, q = lane>>4;
  const int wm = (wave&1)<<6, wn = (wave>>1)<<6;
  const int sr = tid & 127;        // staging row
  const int kc = (tid>>7)<<4;      // A staging k chunk (0 or 16)
  const int sel = tid>>7;          // B staging: 0 = hi, 1 = lo

  f32x4 acc[4][4];
  #pragma unroll
  for (int i=0;i<4;i++)
    #pragma unroll
    for (int j=0;j<4;j++)
      #pragma unroll
      for (int t=0;t<4;t++) acc[i][j][t]=0.f;

  for (int k0 = 0; k0 < K; k0 += 32){
    // ---- stage A (fp32 -> hi/lo bf16), 16 elems/thread
    {
      const float* ap = A + (size_t)(m0+sr)*K + k0 + kc;
      float f[16];
      *(float4*)&f[0]  = *(const float4*)(ap+0);
      *(float4*)&f[4]  = *(const float4*)(ap+4);
      *(float4*)&f[8]  = *(const float4*)(ap+8);
      *(float4*)&f[12] = *(const float4*)(ap+12);
      u16 hh[16], ll[16];
      #pragma unroll
      for (int t=0;t<16;t++){
        u16 h = bf16_rne(f[t]);
        hh[t]=h; ll[t]=bf16_rne(f[t]-bf16_f(h));
      }
      int o = sr*40 + kc;
      *(short8*)&AsH[o]   = *(short8*)&hh[0];
      *(short8*)&AsH[o+8] = *(short8*)&hh[8];
      *(short8*)&AsL[o]   = *(short8*)&ll[0];
      *(short8*)&AsL[o+8] = *(short8*)&ll[8];
    }
    // ---- stage B: pure copy of pre-split weights (32 u16/thread)
    {
      const u16* src = (sel ? WL : WH) + (size_t)(n0+sr)*K + k0;
      u16* dst = (sel ? BsL : BsH) + sr*40;
      #pragma unroll
      for (int c=0;c<4;c++)
        *(short8*)&dst[c*8] = *(const short8*)&src[c*8];
    }
    __syncthreads();

    short8 aH[4], aL[4], bH[4], bL[4];
    #pragma unroll
    for (int i=0;i<4;i++){
      int o = (wm + 16*i + r)*40 + q*8;
      aH[i] = *(const short8*)&AsH[o];
      aL[i] = *(const short8*)&AsL[o];
    }
    #pragma unroll
    for (int j=0;j<4;j++){
      int o = (wn + 16*j + r)*40 + q*8;
      bH[j] = *(const short8*)&BsH[o];
      bL[j] = *(const short8*)&BsL[o];
    }
    #pragma unroll
    for (int i=0;i<4;i++)
      #pragma unroll
      for (int j=0;j<4;j++){
        acc[i][j] = __builtin_amdgcn_mfma_f32_16x16x32_bf16(aH[i], bH[j], acc[i][j], 0,0,0);
        acc[i][j] = __builtin_amdgcn_mfma_f32_16x16x32_bf16(aH[i], bL[j], acc[i][j], 0,0,0);
        acc[i][j] = __builtin_amdgcn_mfma_f32_16x16x32_bf16(aL[i], bH[j], acc[i][j], 0,0,0);
      }
    __syncthreads();
  }

  // epilogue: D col(n) = lane&15, row(m) = 4q+reg
  #pragma unroll
  for (int j=0;j<4;j++){
    int n_out = n0 + wn + 16*j + r;
    float bv = bias ? bias[n_out] : 0.f;
    #pragma unroll
    for (int i=0;i<4;i++){
      #pragma unroll
      for (int reg=0;reg<4;reg++){
        int m_out = m0 + wm + 16*i + 4*q + reg;
        float v = acc[i][j][reg] + bv;
        if (EPI & 1) v *= sigm(v);
        size_t o = (size_t)m_out*N + n_out;
        if (EPI & 2) C[o] += v; else C[o] = v;
      }
    }
  }
}

// ---------------------------------------------------------------------------
// xproj GEMM: DBC[4096][36] = U[4096][1536] @ xw[1536][36], MFMA bf16x3.
// Pre-split xwT[48][1536] (rows 36..47 zero). One wave per 16 rows,
// fragments loaded straight from global (no LDS). grid=256, block=64.
// ---------------------------------------------------------------------------
__global__ __launch_bounds__(64) void xgemm_k(
    const float* __restrict__ A, const u16* __restrict__ XH,
    const u16* __restrict__ XL, float* __restrict__ DBC)
{
  int m0 = blockIdx.x*16;
  int lane = threadIdx.x;
  int r = lane&15, q = lane>>4;
  f32x4 acc[3];
  #pragma unroll
  for (int j=0;j<3;j++)
    #pragma unroll
    for (int t=0;t<4;t++) acc[j][t]=0.f;

  for (int k0 = 0; k0 < EDIM; k0 += 32){
    const float* ap = A + (size_t)(m0+r)*EDIM + k0 + q*8;
    float f[8];
    *(float4*)&f[0] = *(const float4*)(ap+0);
    *(float4*)&f[4] = *(const float4*)(ap+4);
    short8 ah, al;
    #pragma unroll
    for (int t=0;t<8;t++){
      u16 h = bf16_rne(f[t]);
      ah[t] = (short)h;
      al[t] = (short)bf16_rne(f[t]-bf16_f(h));
    }
    #pragma unroll
    for (int j=0;j<3;j++){
      size_t o = (size_t)(16*j+r)*EDIM + k0 + q*8;
      short8 bh = *(const short8*)&XH[o];
      short8 bl = *(const short8*)&XL[o];
      acc[j] = __builtin_amdgcn_mfma_f32_16x16x32_bf16(ah, bh, acc[j], 0,0,0);
      acc[j] = __builtin_amdgcn_mfma_f32_16x16x32_bf16(ah, bl, acc[j], 0,0,0);
      acc[j] = __builtin_amdgcn_mfma_f32_16x16x32_bf16(al, bh, acc[j], 0,0,0);
    }
  }
  #pragma unroll
  for (int j=0;j<3;j++){
    int n = 16*j + r;
    if (n < 36){
      #pragma unroll
      for (int reg=0;reg<4;reg++){
        int m = m0 + 4*q + reg;
        DBC[(size_t)m*36 + n] = acc[j][reg];
      }
    }
  }
}

// ---------------------------------------------------------------------------
__global__ __launch_bounds__(256) void embed_k(
    const int* __restrict__ ids, const float* __restrict__ tok,
    const float* __restrict__ pos, float* __restrict__ HS)
{
  int idx = blockIdx.x*256 + threadIdx.x;
  int h = idx % HDIM; int t = idx / HDIM;
  int lpos = t % LSEQ;
  int id = ids[t];
  HS[idx] = tok[id*HDIM + h] + pos[lpos*HDIM + h];
}

// ---------------------------------------------------------------------------
template<bool OUT>
__global__ __launch_bounds__(256) void ln_t_k(
    const float* __restrict__ X, const float* __restrict__ w,
    const float* __restrict__ b, float* __restrict__ O)
{
  int t = blockIdx.x;
  const float* x = X + (size_t)t*HDIM;
  float s=0.f, s2=0.f;
  for (int i=threadIdx.x; i<HDIM; i+=256){ float v=x[i]; s+=v; s2+=v*v; }
  #pragma unroll
  for (int off=32; off; off>>=1){ s += __shfl_down(s,off,64); s2 += __shfl_down(s2,off,64); }
  __shared__ float rs[4], rs2[4], mv[2];
  int lane = threadIdx.x & 63, wv = threadIdx.x >> 6;
  if (!lane){ rs[wv]=s; rs2[wv]=s2; }
  __syncthreads();
  if (!threadIdx.x){
    float a = rs[0]+rs[1]+rs[2]+rs[3];
    float c = rs2[0]+rs2[1]+rs2[2]+rs2[3];
    float m = a/HDIM;
    mv[0]=m; mv[1]=rsqrtf(c/HDIM - m*m + 1e-5f);
  }
  __syncthreads();
  float m = mv[0], r = mv[1];
  for (int i=threadIdx.x; i<HDIM; i+=256)
    O[(size_t)t*HDIM+i] = (x[i]-m)*r*w[i] + b[i];
}

// ---------------------------------------------------------------------------
__global__ __launch_bounds__(256) void conv_silu_k(
    const float* __restrict__ PROJ, const float* __restrict__ cw,
    const float* __restrict__ cb, float* __restrict__ U)
{
  int idx = blockIdx.x*256 + threadIdx.x;
  int e = idx % EDIM; int t = idx / EDIM;
  int l = t % LSEQ; int tb = t - l;
  float acc = cb[e];
  #pragma unroll
  for (int j=0;j<4;j++){
    int tt = l + j - 3;
    if (tt >= 0) acc += PROJ[(size_t)(tb+tt)*(2*EDIM) + e] * cw[e*4+j];
  }
  U[idx] = acc * sigm(acc);
}

// ---------------------------------------------------------------------------
__global__ __launch_bounds__(256) void dt_k(
    const float* __restrict__ DBC, const float* __restrict__ dtw,
    const float* __restrict__ dtb, float* __restrict__ DT)
{
  int idx = blockIdx.x*256 + threadIdx.x;
  int e = idx % EDIM; int t = idx / EDIM;
  const float* d = DBC + (size_t)t*36;
  float v = dtb[e];
  #pragma unroll
  for (int r=0;r<4;r++) v += d[r]*dtw[r*EDIM+e];
  v = (v > 20.f) ? v : log1pf(__expf(v));
  DT[(size_t)t*(2*EDIM) + e] = v;
}

// ---------------------------------------------------------------------------
// Chunked parallel selective scan (round 3). Y may alias U (in-place safe:
// each U element is read for the last time in the iteration that writes it).
// ---------------------------------------------------------------------------
__global__ __launch_bounds__(256) void scan2_k(
    const float* __restrict__ U, const float* __restrict__ PROJ,
    const float* __restrict__ DBC, const float* __restrict__ Alog,
    const float* __restrict__ Dp, float* __restrict__ Y)
{
  const int CH = LSEQ/16;
  int ch = blockIdx.x;
  int e = ch % EDIM, b = ch / EDIM;
  int tid = threadIdx.x;
  int n = tid & 15, j = tid >> 4;

  float a = -__expf(Alog[e*NST + n]);
  size_t base = (size_t)b*LSEQ;
  int t0 = j*CH;

  __shared__ float Pl[16][17], Sl[16][17], Hin[16][17];

  float P = 1.f, h = 0.f;
  for (int t = t0; t < t0+CH; t++){
    size_t tok = base + t;
    float dt = PROJ[tok*(2*EDIM) + e];
    float u  = U[tok*EDIM + e];
    float Bn = DBC[tok*36 + 4 + n];
    float dA = __expf(dt*a);
    P *= dA;
    h = h*dA + dt*u*Bn;
  }
  Pl[j][n] = P; Sl[j][n] = h;
  __syncthreads();

  if (tid < 16){
    float hin = 0.f;
    #pragma unroll
    for (int jj = 0; jj < 16; jj++){
      Hin[jj][tid] = hin;
      hin = Pl[jj][tid]*hin + Sl[jj][tid];
    }
  }
  __syncthreads();

  h = Hin[j][n];
  float dcf = Dp[e];
  for (int t = t0; t < t0+CH; t++){
    size_t tok = base + t;
    float dt = PROJ[tok*(2*EDIM) + e];
    float u  = U[tok*EDIM + e];
    float Bn = DBC[tok*36 + 4 + n];
    float Cn = DBC[tok*36 + 20 + n];
    float dA = __expf(dt*a);
    h = h*dA + dt*u*Bn;
    float v = h*Cn;
    v += __shfl_xor(v, 1, 64);
    v += __shfl_xor(v, 2, 64);
    v += __shfl_xor(v, 4, 64);
    v += __shfl_xor(v, 8, 64);
    if (n == 0){
      float g = PROJ[tok*(2*EDIM) + EDIM + e];
      Y[tok*EDIM + e] = (v + u*dcf)*sigm(g);
    }
  }
}

// HS += (FB0 + FB1 + FB2)/6
__global__ __launch_bounds__(256) void addscale3_k(
    float* __restrict__ HS, const float* __restrict__ FB)
{
  const size_t S = (size_t)BLTOK*HDIM;
  size_t i = blockIdx.x*256 + threadIdx.x;
  HS[i] += (FB[i] + FB[i+S] + FB[i+2*S]) * (0.5f/3.0f);
}

// ---------------------------------------------------------------------------
extern "C" void kernel_launch(void* const* d_in, const int* in_sizes, int n_in,
                              void* d_out, int out_size, void* d_ws, size_t ws_size,
                              hipStream_t stream)
{
  const int*   ids      = (const int*)d_in[0];
  const float* tok_emb  = (const float*)d_in[1];
  const float* pos_emb  = (const float*)d_in[2];
  const float* ln_w     = (const float*)d_in[3];
  const float* ln_b     = (const float*)d_in[4];
  const float* in_w     = (const float*)d_in[5];
  const float* in_b     = (const float*)d_in[6];
  const float* conv_w   = (const float*)d_in[7];
  const float* conv_b   = (const float*)d_in[8];
  const float* xproj_w  = (const float*)d_in[9];
  const float* dt_w     = (const float*)d_in[10];
  const float* dt_b     = (const float*)d_in[11];
  const float* A_log    = (const float*)d_in[12];
  const float* Dp       = (const float*)d_in[13];
  const float* out_w    = (const float*)d_in[14];
  const float* out_b    = (const float*)d_in[15];
  const float* frac_w   = (const float*)d_in[16];
  const float* frac_b   = (const float*)d_in[17];
  const float* fln_w    = (const float*)d_in[18];
  const float* fln_b    = (const float*)d_in[19];

  // ---- workspace map (floats), ~110 MB total
  const size_t SZ_HS   = (size_t)BLTOK*HDIM;      // 3,145,728
  const size_t SZ_PROJ = (size_t)BLTOK*2*EDIM;    // 12,582,912
  const size_t SZ_UY   = (size_t)BLTOK*EDIM;      //  6,291,456
  float* HS   = (float*)d_ws;
  float* PROJ = HS   + SZ_HS;
  float* UY   = PROJ + SZ_PROJ;                   // XB, then U, then Y (aliased)
  float* DBC  = UY   + SZ_UY;
  float* WF   = DBC  + (size_t)BLTOK*36;
  // bf16 weight scratch (per layer, rewritten each layer)
  u16* W16  = (u16*)WF;
  u16* inH  = W16;                   // 3072*768
  u16* inL  = inH  + (size_t)3072*768;
  u16* outH = inL  + (size_t)3072*768;   // 768*1536
  u16* outL = outH + (size_t)768*1536;
  u16* frH  = outL + (size_t)768*1536;   // 3*768*768
  u16* frL  = frH  + (size_t)3*768*768;
  u16* xH   = frL  + (size_t)3*768*768;  // 48*1536
  u16* xL   = xH   + (size_t)48*1536;
  // fractal buffers alias PROJ+UY (dead after out-proj)
  float* FB = PROJ;                  // 3 * SZ_HS
  float* FC = PROJ + 3*SZ_HS;        // 3 * SZ_HS (ends exactly at DBC)
  float* XB = UY;                    // LN output (dead after in-proj)

  embed_k<<<(BLTOK*HDIM)/256, 256, 0, stream>>>(ids, tok_emb, pos_emb, HS);

  for (int l = 0; l < NLAYER; l++){
    // ---- per-layer weight prep (transpose + bf16 hi/lo split)
    wprep_k<<<dim3(3072/32, 768/32), 256, 0, stream>>>(
        in_w + (size_t)l*HDIM*2*EDIM, inH, inL, 2*EDIM, 2*EDIM, HDIM);
    wprep_k<<<dim3(768/32, 1536/32), 256, 0, stream>>>(
        out_w + (size_t)l*EDIM*HDIM, outH, outL, HDIM, HDIM, EDIM);
    wprep_k<<<dim3(768/32, 768/32, 3), 256, 0, stream>>>(
        frac_w + (size_t)l*3*HDIM*HDIM, frH, frL, HDIM, HDIM, HDIM);
    wprep_k<<<dim3(48/32+1, 1536/32), 256, 0, stream>>>(
        xproj_w + (size_t)l*EDIM*36, xH, xL, 36, 48, EDIM);

    ln_t_k<false><<<BLTOK, 256, 0, stream>>>(HS, ln_w + l*HDIM, ln_b + l*HDIM, XB);

    // proj = LN(hs) @ in_w + in_b   [4096 x 768 x 3072]
    mgemm2_k<0><<<dim3((2*EDIM)/128, BLTOK/128), 256, 0, stream>>>(
        XB, inH, inL, in_b + l*2*EDIM, PROJ, 2*EDIM, HDIM, 0,0,0,0);

    conv_silu_k<<<(BLTOK*EDIM)/256, 256, 0, stream>>>(
        PROJ, conv_w + l*EDIM*4, conv_b + l*EDIM, UY);

    // dbc = u @ xproj_w   [4096 x 1536 x 36]
    xgemm_k<<<BLTOK/16, 64, 0, stream>>>(UY, xH, xL, DBC);

    dt_k<<<(BLTOK*EDIM)/256, 256, 0, stream>>>(
        DBC, dt_w + l*4*EDIM, dt_b + l*EDIM, PROJ);

    // selective scan (Y in-place over U)
    scan2_k<<<BATCH*EDIM, 256, 0, stream>>>(
        UY, PROJ, DBC, A_log + (size_t)l*EDIM*NST, Dp + l*EDIM, UY);

    // hs += y @ out_w + out_b   [4096 x 1536 x 768]
    mgemm2_k<2><<<dim3(HDIM/128, BLTOK/128), 256, 0, stream>>>(
        UY, outH, outL, out_b + l*HDIM, HS, HDIM, EDIM, 0,0,0,0);

    // fractal: 3 branches batched via grid.z, 3 chained stages
    const size_t zW = (size_t)HDIM*HDIM;
    mgemm2_k<1><<<dim3(HDIM/128, BLTOK/128, 3), 256, 0, stream>>>(
        HS, frH, frL, frac_b + (size_t)l*3*HDIM, FB, HDIM, HDIM,
        0, zW, HDIM, SZ_HS);
    mgemm2_k<1><<<dim3(HDIM/128, BLTOK/128, 3), 256, 0, stream>>>(
        FB, frH, frL, frac_b + (size_t)l*3*HDIM, FC, HDIM, HDIM,
        SZ_HS, zW, HDIM, SZ_HS);
    mgemm2_k<1><<<dim3(HDIM/128, BLTOK/128, 3), 256, 0, stream>>>(
        FC, frH, frL, frac_b + (size_t)l*3*HDIM, FB, HDIM, HDIM,
        SZ_HS, zW, HDIM, SZ_HS);

    addscale3_k<<<(BLTOK*HDIM)/256, 256, 0, stream>>>(HS, FB);
  }

  ln_t_k<true><<<BLTOK, 256, 0, stream>>>(HS, fln_w, fln_b, (float*)d_out);
}

// Round 6
// 6917.829 us; speedup vs baseline: 3.4138x; 1.1883x over previous
//
#include <hip/hip_runtime.h>
#include <hip/hip_bf16.h>

#define NLAYER 8
#define HDIM   768
#define EDIM   1536
#define NST    16
#define LSEQ   2048
#define BATCH  2
#define BLTOK  (BATCH*LSEQ)   /* 4096 tokens */
#define NCH    (BATCH*EDIM)   /* 3072 scan channels */
#define NCHK   16             /* scan time chunks */

typedef unsigned short u16;
typedef short  short8  __attribute__((ext_vector_type(8)));
typedef float  f32x4   __attribute__((ext_vector_type(4)));

__device__ __forceinline__ float sigm(float x){ return 1.0f/(1.0f+__expf(-x)); }

__device__ __forceinline__ u16 bf16_rne(float x){
  unsigned u = __float_as_uint(x);
  return (u16)((u + 0x7fffu + ((u>>16)&1u)) >> 16);
}
__device__ __forceinline__ float bf16_f(u16 h){
  return __uint_as_float(((unsigned)h)<<16);
}
__device__ __forceinline__ unsigned packhl(float v){
  u16 h = bf16_rne(v);
  u16 l = bf16_rne(v - bf16_f(h));
  return (unsigned)h | ((unsigned)l<<16);
}

// ---------------------------------------------------------------------------
// Weight prep: W[K][Nsrc] fp32 -> H/L[Ndst][K] bf16 hi/lo (transposed).
// ---------------------------------------------------------------------------
__global__ __launch_bounds__(256) void wprep_k(
    const float* __restrict__ W, u16* __restrict__ H, u16* __restrict__ L,
    int Nsrc, int Ndst, int K)
{
  __shared__ float T[32][33];
  int z = blockIdx.z;
  W += (size_t)z*K*Nsrc; H += (size_t)z*Ndst*K; L += (size_t)z*Ndst*K;
  int n0 = blockIdx.x*32, k0 = blockIdx.y*32;
  int tx = threadIdx.x&31, ty = threadIdx.x>>5;
  #pragma unroll
  for (int r=0;r<4;r++){
    int kk = ty+8*r, col = n0+tx;
    T[kk][tx] = (col<Nsrc) ? W[(size_t)(k0+kk)*Nsrc+col] : 0.f;
  }
  __syncthreads();
  #pragma unroll
  for (int r=0;r<4;r++){
    int nn = ty+8*r, n = n0+nn, k = k0+tx;
    if (n<Ndst){
      float f = T[tx][nn];
      u16 h = bf16_rne(f);
      H[(size_t)n*K+k] = h;
      L[(size_t)n*K+k] = bf16_rne(f - bf16_f(h));
    }
  }
}

// ---------------------------------------------------------------------------
// Shared MFMA core geometry: tile 128x128, BK=32, 4 waves, 4x4 16x16x32 MFMA.
// EPI bits: 1=SiLU, 2=accumulate fp32, 4=store packed hi|lo u32.
// ---------------------------------------------------------------------------
// mgemm2: A fp32 (split on the fly)
template<int EPI>
__global__ __launch_bounds__(256) void mgemm2_k(
    const float* __restrict__ A, const u16* __restrict__ WH,
    const u16* __restrict__ WL, const float* __restrict__ bias,
    void* __restrict__ Cout, int N, int K,
    size_t zA, size_t zW, size_t zB, size_t zC)
{
  const int z = blockIdx.z;
  A += (size_t)z*zA; WH += (size_t)z*zW; WL += (size_t)z*zW;
  if (bias) bias += (size_t)z*zB;

  __shared__ u16 AsH[128*40], AsL[128*40], BsH[128*40], BsL[128*40];
  const int tid  = threadIdx.x;
  const int m0 = blockIdx.y<<7, n0 = blockIdx.x<<7;
  const int wave = tid>>6, lane = tid&63;
  const int r = lane&15, q = lane>>4;
  const int wm = (wave&1)<<6, wn = (wave>>1)<<6;
  const int sr = tid & 127;
  const int kc = (tid>>7)<<4;
  const int sel = tid>>7;

  f32x4 acc[4][4];
  #pragma unroll
  for (int i=0;i<4;i++)
    #pragma unroll
    for (int j=0;j<4;j++)
      #pragma unroll
      for (int t=0;t<4;t++) acc[i][j][t]=0.f;

  for (int k0 = 0; k0 < K; k0 += 32){
    {
      const float* ap = A + (size_t)(m0+sr)*K + k0 + kc;
      float f[16];
      *(float4*)&f[0]  = *(const float4*)(ap+0);
      *(float4*)&f[4]  = *(const float4*)(ap+4);
      *(float4*)&f[8]  = *(const float4*)(ap+8);
      *(float4*)&f[12] = *(const float4*)(ap+12);
      u16 hh[16], ll[16];
      #pragma unroll
      for (int t=0;t<16;t++){
        u16 h = bf16_rne(f[t]);
        hh[t]=h; ll[t]=bf16_rne(f[t]-bf16_f(h));
      }
      int o = sr*40 + kc;
      *(short8*)&AsH[o]   = *(short8*)&hh[0];
      *(short8*)&AsH[o+8] = *(short8*)&hh[8];
      *(short8*)&AsL[o]   = *(short8*)&ll[0];
      *(short8*)&AsL[o+8] = *(short8*)&ll[8];
    }
    {
      const u16* src = (sel ? WL : WH) + (size_t)(n0+sr)*K + k0;
      u16* dst = (sel ? BsL : BsH) + sr*40;
      #pragma unroll
      for (int c=0;c<4;c++)
        *(short8*)&dst[c*8] = *(const short8*)&src[c*8];
    }
    __syncthreads();

    short8 aH[4], aL[4], bH[4], bL[4];
    #pragma unroll
    for (int i=0;i<4;i++){
      int o = (wm + 16*i + r)*40 + q*8;
      aH[i] = *(const short8*)&AsH[o];
      aL[i] = *(const short8*)&AsL[o];
    }
    #pragma unroll
    for (int j=0;j<4;j++){
      int o = (wn + 16*j + r)*40 + q*8;
      bH[j] = *(const short8*)&BsH[o];
      bL[j] = *(const short8*)&BsL[o];
    }
    #pragma unroll
    for (int i=0;i<4;i++)
      #pragma unroll
      for (int j=0;j<4;j++){
        acc[i][j] = __builtin_amdgcn_mfma_f32_16x16x32_bf16(aH[i], bH[j], acc[i][j], 0,0,0);
        acc[i][j] = __builtin_amdgcn_mfma_f32_16x16x32_bf16(aH[i], bL[j], acc[i][j], 0,0,0);
        acc[i][j] = __builtin_amdgcn_mfma_f32_16x16x32_bf16(aL[i], bH[j], acc[i][j], 0,0,0);
      }
    __syncthreads();
  }

  float*    Cf = (float*)Cout    + (size_t)z*zC;
  unsigned* Cp = (unsigned*)Cout + (size_t)z*zC;
  #pragma unroll
  for (int j=0;j<4;j++){
    int n_out = n0 + wn + 16*j + r;
    float bv = bias ? bias[n_out] : 0.f;
    #pragma unroll
    for (int i=0;i<4;i++){
      #pragma unroll
      for (int reg=0;reg<4;reg++){
        int m_out = m0 + wm + 16*i + 4*q + reg;
        float v = acc[i][j][reg] + bv;
        if (EPI & 1) v *= sigm(v);
        size_t o = (size_t)m_out*N + n_out;
        if (EPI & 4)      Cp[o] = packhl(v);
        else if (EPI & 2) Cf[o] += v;
        else              Cf[o] = v;
      }
    }
  }
}

// mgemm3: A pre-packed hi|lo u32, row stride lda
template<int EPI>
__global__ __launch_bounds__(256) void mgemm3_k(
    const unsigned* __restrict__ A, int lda, const u16* __restrict__ WH,
    const u16* __restrict__ WL, const float* __restrict__ bias,
    void* __restrict__ Cout, int N, int K,
    size_t zA, size_t zW, size_t zB, size_t zC)
{
  const int z = blockIdx.z;
  A += (size_t)z*zA; WH += (size_t)z*zW; WL += (size_t)z*zW;
  if (bias) bias += (size_t)z*zB;

  __shared__ u16 AsH[128*40], AsL[128*40], BsH[128*40], BsL[128*40];
  const int tid  = threadIdx.x;
  const int m0 = blockIdx.y<<7, n0 = blockIdx.x<<7;
  const int wave = tid>>6, lane = tid&63;
  const int r = lane&15, q = lane>>4;
  const int wm = (wave&1)<<6, wn = (wave>>1)<<6;
  const int sr = tid & 127;
  const int kc = (tid>>7)<<4;
  const int sel = tid>>7;

  f32x4 acc[4][4];
  #pragma unroll
  for (int i=0;i<4;i++)
    #pragma unroll
    for (int j=0;j<4;j++)
      #pragma unroll
      for (int t=0;t<4;t++) acc[i][j][t]=0.f;

  for (int k0 = 0; k0 < K; k0 += 32){
    {
      const unsigned* ap = A + (size_t)(m0+sr)*lda + k0 + kc;
      unsigned x[16];
      *(uint4*)&x[0]  = *(const uint4*)(ap+0);
      *(uint4*)&x[4]  = *(const uint4*)(ap+4);
      *(uint4*)&x[8]  = *(const uint4*)(ap+8);
      *(uint4*)&x[12] = *(const uint4*)(ap+12);
      u16 hh[16], ll[16];
      #pragma unroll
      for (int t=0;t<16;t++){ hh[t] = (u16)(x[t]&0xffffu); ll[t] = (u16)(x[t]>>16); }
      int o = sr*40 + kc;
      *(short8*)&AsH[o]   = *(short8*)&hh[0];
      *(short8*)&AsH[o+8] = *(short8*)&hh[8];
      *(short8*)&AsL[o]   = *(short8*)&ll[0];
      *(short8*)&AsL[o+8] = *(short8*)&ll[8];
    }
    {
      const u16* src = (sel ? WL : WH) + (size_t)(n0+sr)*K + k0;
      u16* dst = (sel ? BsL : BsH) + sr*40;
      #pragma unroll
      for (int c=0;c<4;c++)
        *(short8*)&dst[c*8] = *(const short8*)&src[c*8];
    }
    __syncthreads();

    short8 aH[4], aL[4], bH[4], bL[4];
    #pragma unroll
    for (int i=0;i<4;i++){
      int o = (wm + 16*i + r)*40 + q*8;
      aH[i] = *(const short8*)&AsH[o];
      aL[i] = *(const short8*)&AsL[o];
    }
    #pragma unroll
    for (int j=0;j<4;j++){
      int o = (wn + 16*j + r)*40 + q*8;
      bH[j] = *(const short8*)&BsH[o];
      bL[j] = *(const short8*)&BsL[o];
    }
    #pragma unroll
    for (int i=0;i<4;i++)
      #pragma unroll
      for (int j=0;j<4;j++){
        acc[i][j] = __builtin_amdgcn_mfma_f32_16x16x32_bf16(aH[i], bH[j], acc[i][j], 0,0,0);
        acc[i][j] = __builtin_amdgcn_mfma_f32_16x16x32_bf16(aH[i], bL[j], acc[i][j], 0,0,0);
        acc[i][j] = __builtin_amdgcn_mfma_f32_16x16x32_bf16(aL[i], bH[j], acc[i][j], 0,0,0);
      }
    __syncthreads();
  }

  float*    Cf = (float*)Cout    + (size_t)z*zC;
  unsigned* Cp = (unsigned*)Cout + (size_t)z*zC;
  #pragma unroll
  for (int j=0;j<4;j++){
    int n_out = n0 + wn + 16*j + r;
    float bv = bias ? bias[n_out] : 0.f;
    #pragma unroll
    for (int i=0;i<4;i++){
      #pragma unroll
      for (int reg=0;reg<4;reg++){
        int m_out = m0 + wm + 16*i + 4*q + reg;
        float v = acc[i][j][reg] + bv;
        if (EPI & 1) v *= sigm(v);
        size_t o = (size_t)m_out*N + n_out;
        if (EPI & 4)      Cp[o] = packhl(v);
        else if (EPI & 2) Cf[o] += v;
        else              Cf[o] = v;
      }
    }
  }
}

// ---------------------------------------------------------------------------
// xproj GEMM: DBC[4096][36] = U[4096][1536] @ xw; pre-split xwT[48][1536].
// ---------------------------------------------------------------------------
__global__ __launch_bounds__(64) void xgemm_k(
    const float* __restrict__ A, const u16* __restrict__ XH,
    const u16* __restrict__ XL, float* __restrict__ DBC)
{
  int m0 = blockIdx.x*16;
  int lane = threadIdx.x;
  int r = lane&15, q = lane>>4;
  f32x4 acc[3];
  #pragma unroll
  for (int j=0;j<3;j++)
    #pragma unroll
    for (int t=0;t<4;t++) acc[j][t]=0.f;

  for (int k0 = 0; k0 < EDIM; k0 += 32){
    const float* ap = A + (size_t)(m0+r)*EDIM + k0 + q*8;
    float f[8];
    *(float4*)&f[0] = *(const float4*)(ap+0);
    *(float4*)&f[4] = *(const float4*)(ap+4);
    short8 ah, al;
    #pragma unroll
    for (int t=0;t<8;t++){
      u16 h = bf16_rne(f[t]);
      ah[t] = (short)h;
      al[t] = (short)bf16_rne(f[t]-bf16_f(h));
    }
    #pragma unroll
    for (int j=0;j<3;j++){
      size_t o = (size_t)(16*j+r)*EDIM + k0 + q*8;
      short8 bh = *(const short8*)&XH[o];
      short8 bl = *(const short8*)&XL[o];
      acc[j] = __builtin_amdgcn_mfma_f32_16x16x32_bf16(ah, bh, acc[j], 0,0,0);
      acc[j] = __builtin_amdgcn_mfma_f32_16x16x32_bf16(ah, bl, acc[j], 0,0,0);
      acc[j] = __builtin_amdgcn_mfma_f32_16x16x32_bf16(al, bh, acc[j], 0,0,0);
    }
  }
  #pragma unroll
  for (int j=0;j<3;j++){
    int n = 16*j + r;
    if (n < 36){
      #pragma unroll
      for (int reg=0;reg<4;reg++){
        int m = m0 + 4*q + reg;
        DBC[(size_t)m*36 + n] = acc[j][reg];
      }
    }
  }
}

// ---------------------------------------------------------------------------
__global__ __launch_bounds__(256) void embed_k(
    const int* __restrict__ ids, const float* __restrict__ tok,
    const float* __restrict__ pos, float* __restrict__ HS)
{
  int idx = blockIdx.x*256 + threadIdx.x;
  int h = idx % HDIM; int t = idx / HDIM;
  int lpos = t % LSEQ;
  int id = ids[t];
  HS[idx] = tok[id*HDIM + h] + pos[lpos*HDIM + h];
}

// ---------------------------------------------------------------------------
// LayerNorm; PACK=1 -> packed hi|lo u32 output, else fp32.
// ---------------------------------------------------------------------------
template<int PACK>
__global__ __launch_bounds__(256) void ln_k(
    const float* __restrict__ X, const float* __restrict__ w,
    const float* __restrict__ b, void* __restrict__ O)
{
  int t = blockIdx.x;
  const float* x = X + (size_t)t*HDIM;
  float s=0.f, s2=0.f;
  for (int i=threadIdx.x; i<HDIM; i+=256){ float v=x[i]; s+=v; s2+=v*v; }
  #pragma unroll
  for (int off=32; off; off>>=1){ s += __shfl_down(s,off,64); s2 += __shfl_down(s2,off,64); }
  __shared__ float rs[4], rs2[4], mv[2];
  int lane = threadIdx.x & 63, wv = threadIdx.x >> 6;
  if (!lane){ rs[wv]=s; rs2[wv]=s2; }
  __syncthreads();
  if (!threadIdx.x){
    float a = rs[0]+rs[1]+rs[2]+rs[3];
    float c = rs2[0]+rs2[1]+rs2[2]+rs2[3];
    float m = a/HDIM;
    mv[0]=m; mv[1]=rsqrtf(c/HDIM - m*m + 1e-5f);
  }
  __syncthreads();
  float m = mv[0], r = mv[1];
  for (int i=threadIdx.x; i<HDIM; i+=256){
    float v = (x[i]-m)*r*w[i] + b[i];
    if (PACK) ((unsigned*)O)[(size_t)t*HDIM+i] = packhl(v);
    else      ((float*)O)[(size_t)t*HDIM+i] = v;
  }
}

// ---------------------------------------------------------------------------
__global__ __launch_bounds__(256) void conv_silu_k(
    const float* __restrict__ PROJ, const float* __restrict__ cw,
    const float* __restrict__ cb, float* __restrict__ U)
{
  int idx = blockIdx.x*256 + threadIdx.x;
  int e = idx % EDIM; int t = idx / EDIM;
  int l = t % LSEQ; int tb = t - l;
  float acc = cb[e];
  #pragma unroll
  for (int j=0;j<4;j++){
    int tt = l + j - 3;
    if (tt >= 0) acc += PROJ[(size_t)(tb+tt)*(2*EDIM) + e] * cw[e*4+j];
  }
  U[idx] = acc * sigm(acc);
}

// ---------------------------------------------------------------------------
// Coalesced chunked scan, 3 kernels. Thread = (channel, chunk), 16 states
// in registers. Lanes = consecutive channels -> coalesced u/dt/gate; B/C/dt
// rows wave-uniform (DBC is L2-resident). dt computed on the fly (softplus).
// ---------------------------------------------------------------------------
__global__ __launch_bounds__(256) void scanA_k(
    const float* __restrict__ U, const float* __restrict__ DBC,
    const float* __restrict__ Alog, const float* __restrict__ dtw,
    const float* __restrict__ dtb, float* __restrict__ PSP,
    float* __restrict__ PSS)
{
  const int CH = LSEQ/NCHK;
  int el = threadIdx.x & 63, jj = threadIdx.x >> 6;
  int ch = blockIdx.x*64 + el;
  int j  = blockIdx.y*4 + jj;
  int e = ch % EDIM, b = ch / EDIM;

  float a[16], P[16], S[16];
  #pragma unroll
  for (int n=0;n<16;n++){ a[n] = -__expf(Alog[e*NST+n]); P[n]=1.f; S[n]=0.f; }
  float w0=dtw[e], w1=dtw[EDIM+e], w2=dtw[2*EDIM+e], w3=dtw[3*EDIM+e];
  float db=dtb[e];
  size_t base=(size_t)b*LSEQ;

  for (int t=j*CH; t<j*CH+CH; t++){
    size_t tok = base+t;
    float4 d4 = *(const float4*)&DBC[tok*36];
    float4 B0 = *(const float4*)&DBC[tok*36+4];
    float4 B1 = *(const float4*)&DBC[tok*36+8];
    float4 B2 = *(const float4*)&DBC[tok*36+12];
    float4 B3 = *(const float4*)&DBC[tok*36+16];
    float dt = d4.x*w0 + d4.y*w1 + d4.z*w2 + d4.w*w3 + db;
    dt = (dt>20.f)?dt:log1pf(__expf(dt));
    float du = dt * U[tok*EDIM+e];
    float Bv[16];
    *(float4*)&Bv[0]=B0; *(float4*)&Bv[4]=B1; *(float4*)&Bv[8]=B2; *(float4*)&Bv[12]=B3;
    #pragma unroll
    for (int n=0;n<16;n++){
      float dA = __expf(dt*a[n]);
      P[n]*=dA; S[n]=S[n]*dA + du*Bv[n];
    }
  }
  #pragma unroll
  for (int n=0;n<16;n++){
    PSP[(size_t)(j*16+n)*NCH + ch] = P[n];
    PSS[(size_t)(j*16+n)*NCH + ch] = S[n];
  }
}

__global__ __launch_bounds__(256) void scanB_k(
    const float* __restrict__ PSP, const float* __restrict__ PSS,
    float* __restrict__ HIN)
{
  int idx = blockIdx.x*256 + threadIdx.x;   // over NCH*16
  int n = idx / NCH, ch = idx % NCH;
  float hin = 0.f;
  #pragma unroll
  for (int jj=0;jj<NCHK;jj++){
    size_t o = (size_t)(jj*16+n)*NCH + ch;
    HIN[o] = hin;
    hin = PSP[o]*hin + PSS[o];
  }
}

__global__ __launch_bounds__(256) void scanC_k(
    const float* __restrict__ U, const float* __restrict__ DBC,
    const float* __restrict__ Alog, const float* __restrict__ dtw,
    const float* __restrict__ dtb, const float* __restrict__ HIN,
    const float* __restrict__ Dp, float* __restrict__ PROJ)
{
  const int CH = LSEQ/NCHK;
  int el = threadIdx.x & 63, jj = threadIdx.x >> 6;
  int ch = blockIdx.x*64 + el;
  int j  = blockIdx.y*4 + jj;
  int e = ch % EDIM, b = ch / EDIM;

  float a[16], h[16];
  #pragma unroll
  for (int n=0;n<16;n++){
    a[n] = -__expf(Alog[e*NST+n]);
    h[n] = HIN[(size_t)(j*16+n)*NCH + ch];
  }
  float w0=dtw[e], w1=dtw[EDIM+e], w2=dtw[2*EDIM+e], w3=dtw[3*EDIM+e];
  float db=dtb[e], dcf=Dp[e];
  size_t base=(size_t)b*LSEQ;
  unsigned* Yp = (unsigned*)PROJ;

  for (int t=j*CH; t<j*CH+CH; t++){
    size_t tok = base+t;
    float4 d4 = *(const float4*)&DBC[tok*36];
    float4 B0 = *(const float4*)&DBC[tok*36+4];
    float4 B1 = *(const float4*)&DBC[tok*36+8];
    float4 B2 = *(const float4*)&DBC[tok*36+12];
    float4 B3 = *(const float4*)&DBC[tok*36+16];
    float4 C0 = *(const float4*)&DBC[tok*36+20];
    float4 C1 = *(const float4*)&DBC[tok*36+24];
    float4 C2 = *(const float4*)&DBC[tok*36+28];
    float4 C3 = *(const float4*)&DBC[tok*36+32];
    float dt = d4.x*w0 + d4.y*w1 + d4.z*w2 + d4.w*w3 + db;
    dt = (dt>20.f)?dt:log1pf(__expf(dt));
    float u = U[tok*EDIM+e];
    float du = dt * u;
    float Bv[16], Cv[16];
    *(float4*)&Bv[0]=B0; *(float4*)&Bv[4]=B1; *(float4*)&Bv[8]=B2; *(float4*)&Bv[12]=B3;
    *(float4*)&Cv[0]=C0; *(float4*)&Cv[4]=C1; *(float4*)&Cv[8]=C2; *(float4*)&Cv[12]=C3;
    float y = 0.f;
    #pragma unroll
    for (int n=0;n<16;n++){
      float dA = __expf(dt*a[n]);
      h[n] = h[n]*dA + du*Bv[n];
      y += h[n]*Cv[n];
    }
    float g = PROJ[tok*(2*EDIM) + EDIM + e];
    Yp[tok*(2*EDIM) + e] = packhl((y + u*dcf)*sigm(g));
  }
}

// HS += (FB0 + FB1 + FB2)/6
__global__ __launch_bounds__(256) void addscale3_k(
    float* __restrict__ HS, const float* __restrict__ FB)
{
  const size_t S = (size_t)BLTOK*HDIM;
  size_t i = blockIdx.x*256 + threadIdx.x;
  HS[i] += (FB[i] + FB[i+S] + FB[i+2*S]) * (0.5f/3.0f);
}

// ---------------------------------------------------------------------------
extern "C" void kernel_launch(void* const* d_in, const int* in_sizes, int n_in,
                              void* d_out, int out_size, void* d_ws, size_t ws_size,
                              hipStream_t stream)
{
  const int*   ids      = (const int*)d_in[0];
  const float* tok_emb  = (const float*)d_in[1];
  const float* pos_emb  = (const float*)d_in[2];
  const float* ln_w     = (const float*)d_in[3];
  const float* ln_b     = (const float*)d_in[4];
  const float* in_w     = (const float*)d_in[5];
  const float* in_b     = (const float*)d_in[6];
  const float* conv_w   = (const float*)d_in[7];
  const float* conv_b   = (const float*)d_in[8];
  const float* xproj_w  = (const float*)d_in[9];
  const float* dt_w     = (const float*)d_in[10];
  const float* dt_b     = (const float*)d_in[11];
  const float* A_log    = (const float*)d_in[12];
  const float* Dp       = (const float*)d_in[13];
  const float* out_w    = (const float*)d_in[14];
  const float* out_b    = (const float*)d_in[15];
  const float* frac_w   = (const float*)d_in[16];
  const float* frac_b   = (const float*)d_in[17];
  const float* fln_w    = (const float*)d_in[18];
  const float* fln_b    = (const float*)d_in[19];

  // ---- workspace map (~119.6 MB)
  const size_t F_HS   = (size_t)BLTOK*HDIM;      // 3,145,728
  const size_t F_PROJ = (size_t)BLTOK*2*EDIM;    // 12,582,912
  const size_t F_R1   = (size_t)BLTOK*EDIM;      //  6,291,456
  float* HS   = (float*)d_ws;
  float* PROJ = HS   + F_HS;
  float* R1   = PROJ + F_PROJ;                   // XBp, then U
  float* DBC  = R1   + F_R1;
  u16* W16  = (u16*)(DBC + (size_t)BLTOK*36);
  u16* inH  = W16;
  u16* inL  = inH  + (size_t)2359296;
  u16* outH = inL  + (size_t)2359296;
  u16* outL = outH + (size_t)1179648;
  u16* frH  = outL + (size_t)1179648;
  u16* frL  = frH  + (size_t)1769472;
  u16* xH   = frL  + (size_t)1769472;
  u16* xL   = xH   + (size_t)73728;
  float* PSP = (float*)(xL + (size_t)73728);
  float* PSS = PSP + (size_t)NCH*NCHK*16/16*16;  // 786,432
  float* HIN = PSS + (size_t)786432;
  // aliases
  unsigned* XBp = (unsigned*)R1;                 // packed LN out (12.6 MB)
  float*    U   = R1;                            // fp32 conv out (25 MB)
  unsigned* S1  = (unsigned*)PROJ;               // fractal stage1 out (packed)
  unsigned* S2  = S1 + (size_t)3*F_HS;           // stage2 out (spans into R1)
  float*    FB  = PROJ;                          // stage3 out fp32 (3*F_HS)

  embed_k<<<(BLTOK*HDIM)/256, 256, 0, stream>>>(ids, tok_emb, pos_emb, HS);

  const size_t zWf = (size_t)HDIM*HDIM;
  for (int l = 0; l < NLAYER; l++){
    wprep_k<<<dim3(3072/32, 768/32), 256, 0, stream>>>(
        in_w + (size_t)l*HDIM*2*EDIM, inH, inL, 2*EDIM, 2*EDIM, HDIM);
    wprep_k<<<dim3(768/32, 1536/32), 256, 0, stream>>>(
        out_w + (size_t)l*EDIM*HDIM, outH, outL, HDIM, HDIM, EDIM);
    wprep_k<<<dim3(768/32, 768/32, 3), 256, 0, stream>>>(
        frac_w + (size_t)l*3*HDIM*HDIM, frH, frL, HDIM, HDIM, HDIM);
    wprep_k<<<dim3(2, 1536/32), 256, 0, stream>>>(
        xproj_w + (size_t)l*EDIM*36, xH, xL, 36, 48, EDIM);

    // LN -> packed
    ln_k<1><<<BLTOK, 256, 0, stream>>>(HS, ln_w + l*HDIM, ln_b + l*HDIM, XBp);

    // proj = LN(hs) @ in_w + in_b   [4096 x 768 x 3072]
    mgemm3_k<0><<<dim3(24, 32), 256, 0, stream>>>(
        XBp, HDIM, inH, inL, in_b + l*2*EDIM, PROJ, 2*EDIM, HDIM, 0,0,0,0);

    conv_silu_k<<<(BLTOK*EDIM)/256, 256, 0, stream>>>(
        PROJ, conv_w + l*EDIM*4, conv_b + l*EDIM, U);

    // dbc = u @ xproj_w
    xgemm_k<<<BLTOK/16, 64, 0, stream>>>(U, xH, xL, DBC);

    // selective scan (coalesced 3-phase), packed Y into PROJ[:, :E]
    scanA_k<<<dim3(NCH/64, 4), 256, 0, stream>>>(
        U, DBC, A_log + (size_t)l*EDIM*NST, dt_w + (size_t)l*4*EDIM,
        dt_b + (size_t)l*EDIM, PSP, PSS);
    scanB_k<<<(NCH*16)/256, 256, 0, stream>>>(PSP, PSS, HIN);
    scanC_k<<<dim3(NCH/64, 4), 256, 0, stream>>>(
        U, DBC, A_log + (size_t)l*EDIM*NST, dt_w + (size_t)l*4*EDIM,
        dt_b + (size_t)l*EDIM, HIN, Dp + (size_t)l*EDIM, PROJ);

    // hs += y @ out_w + out_b   [4096 x 1536 x 768]
    mgemm3_k<2><<<dim3(6, 32), 256, 0, stream>>>(
        (unsigned*)PROJ, 2*EDIM, outH, outL, out_b + l*HDIM, HS, HDIM, EDIM,
        0,0,0,0);

    // fractal: 3 z-batched stages; S1,S2 packed; stage3 fp32 -> FB
    mgemm2_k<5><<<dim3(6, 32, 3), 256, 0, stream>>>(
        HS, frH, frL, frac_b + (size_t)l*3*HDIM, S1, HDIM, HDIM,
        0, zWf, HDIM, 3*F_HS/3);
    mgemm3_k<5><<<dim3(6, 32, 3), 256, 0, stream>>>(
        S1, HDIM, frH, frL, frac_b + (size_t)l*3*HDIM, S2, HDIM, HDIM,
        F_HS, zWf, HDIM, F_HS);
    mgemm3_k<1><<<dim3(6, 32, 3), 256, 0, stream>>>(
        S2, HDIM, frH, frL, frac_b + (size_t)l*3*HDIM, FB, HDIM, HDIM,
        F_HS, zWf, HDIM, F_HS);

    addscale3_k<<<(BLTOK*HDIM)/256, 256, 0, stream>>>(HS, FB);
  }

  ln_k<0><<<BLTOK, 256, 0, stream>>>(HS, fln_w, fln_b, (float*)d_out);
}

// Round 7
// 5588.487 us; speedup vs baseline: 4.2258x; 1.2379x over previous
//
#include <hip/hip_runtime.h>
#include <hip/hip_bf16.h>

#define NLAYER 8
#define HDIM   768
#define EDIM   1536
#define NST    16
#define LSEQ   2048
#define BATCH  2
#define BLTOK  (BATCH*LSEQ)   /* 4096 tokens */
#define NCH    (BATCH*EDIM)   /* 3072 scan channels */
#define NCHK   16             /* scan time chunks */

typedef unsigned short u16;
typedef short  short8  __attribute__((ext_vector_type(8)));
typedef float  f32x4   __attribute__((ext_vector_type(4)));

__device__ __forceinline__ float sigm(float x){ return 1.0f/(1.0f+__expf(-x)); }

__device__ __forceinline__ u16 bf16_rne(float x){
  unsigned u = __float_as_uint(x);
  return (u16)((u + 0x7fffu + ((u>>16)&1u)) >> 16);
}
__device__ __forceinline__ float bf16_f(u16 h){
  return __uint_as_float(((unsigned)h)<<16);
}
__device__ __forceinline__ unsigned packhl(float v){
  u16 h = bf16_rne(v);
  u16 l = bf16_rne(v - bf16_f(h));
  return (unsigned)h | ((unsigned)l<<16);
}

// ---------------------------------------------------------------------------
// Weight prep: W[K][Nsrc] fp32 -> H/L[Ndst][K] bf16 hi/lo (transposed).
// ---------------------------------------------------------------------------
__global__ __launch_bounds__(256) void wprep_k(
    const float* __restrict__ W, u16* __restrict__ H, u16* __restrict__ L,
    int Nsrc, int Ndst, int K)
{
  __shared__ float T[32][33];
  int z = blockIdx.z;
  W += (size_t)z*K*Nsrc; H += (size_t)z*Ndst*K; L += (size_t)z*Ndst*K;
  int n0 = blockIdx.x*32, k0 = blockIdx.y*32;
  int tx = threadIdx.x&31, ty = threadIdx.x>>5;
  #pragma unroll
  for (int r=0;r<4;r++){
    int kk = ty+8*r, col = n0+tx;
    T[kk][tx] = (col<Nsrc) ? W[(size_t)(k0+kk)*Nsrc+col] : 0.f;
  }
  __syncthreads();
  #pragma unroll
  for (int r=0;r<4;r++){
    int nn = ty+8*r, n = n0+nn, k = k0+tx;
    if (n<Ndst){
      float f = T[tx][nn];
      u16 h = bf16_rne(f);
      H[(size_t)n*K+k] = h;
      L[(size_t)n*K+k] = bf16_rne(f - bf16_f(h));
    }
  }
}

// ---------------------------------------------------------------------------
// Unified MFMA GEMM. Tile 128x128, BK=32, 4 waves, 4x4 of 16x16x32 MFMA.
// AFMT: 0 = A fp32, 1 = A packed hi|lo u32, 2 = A bf16 u16.
// SPLIT: 3 = bf16x3 (fp32-like), 1 = plain bf16.
// SPLITK: bias only applied on z==0.
// EPI bits: 1=SiLU, 2=C+=v, 4=pack u32, 8=store bf16 u16, 16=atomicAdd f32.
// z strides (elements of respective type): zA, zW, zB, zC.
// ---------------------------------------------------------------------------
template<int EPI, int AFMT, int SPLIT, int SPLITK>
__global__ __launch_bounds__(256) void gemm_u(
    const void* __restrict__ Ain, int lda,
    const u16* __restrict__ WH, const u16* __restrict__ WL, int ldw,
    const float* __restrict__ bias, void* __restrict__ Cout,
    int N, int Kloop, size_t zA, size_t zW, size_t zB, size_t zC)
{
  constexpr int NBUF = (SPLIT==3)?4:2;
  __shared__ u16 smem[NBUF*128*40];
  u16* AsH = smem;
  u16* AsL = smem + 128*40;                       // SPLIT==3 only
  u16* BsH = smem + (SPLIT==3?2:1)*128*40;
  u16* BsL = smem + 3*128*40;                     // SPLIT==3 only

  const int z = blockIdx.z;
  WH += (size_t)z*zW; WL += (size_t)z*zW;

  const int tid  = threadIdx.x;
  const int m0 = blockIdx.y<<7, n0 = blockIdx.x<<7;
  const int wave = tid>>6, lane = tid&63;
  const int r = lane&15, q = lane>>4;
  const int wm = (wave&1)<<6, wn = (wave>>1)<<6;
  const int sr = tid & 127;
  const int kc = (tid>>7)<<4;     // 0 or 16
  const int sel = tid>>7;

  f32x4 acc[4][4];
  #pragma unroll
  for (int i=0;i<4;i++)
    #pragma unroll
    for (int j=0;j<4;j++)
      #pragma unroll
      for (int t=0;t<4;t++) acc[i][j][t]=0.f;

  for (int k0 = 0; k0 < Kloop; k0 += 32){
    // ---- stage A: 16 elems at (row sr, k kc)
    {
      int o = sr*40 + kc;
      if constexpr (AFMT == 0){
        const float* ap = (const float*)Ain + (size_t)z*zA + (size_t)(m0+sr)*lda + k0 + kc;
        float f[16];
        *(float4*)&f[0]  = *(const float4*)(ap+0);
        *(float4*)&f[4]  = *(const float4*)(ap+4);
        *(float4*)&f[8]  = *(const float4*)(ap+8);
        *(float4*)&f[12] = *(const float4*)(ap+12);
        u16 hh[16];
        if constexpr (SPLIT == 3){
          u16 ll[16];
          #pragma unroll
          for (int t=0;t<16;t++){
            u16 h = bf16_rne(f[t]); hh[t]=h; ll[t]=bf16_rne(f[t]-bf16_f(h));
          }
          *(short8*)&AsL[o]   = *(short8*)&ll[0];
          *(short8*)&AsL[o+8] = *(short8*)&ll[8];
        } else {
          #pragma unroll
          for (int t=0;t<16;t++) hh[t] = bf16_rne(f[t]);
        }
        *(short8*)&AsH[o]   = *(short8*)&hh[0];
        *(short8*)&AsH[o+8] = *(short8*)&hh[8];
      } else if constexpr (AFMT == 1){
        const unsigned* ap = (const unsigned*)Ain + (size_t)z*zA + (size_t)(m0+sr)*lda + k0 + kc;
        unsigned x[16];
        *(uint4*)&x[0]  = *(const uint4*)(ap+0);
        *(uint4*)&x[4]  = *(const uint4*)(ap+4);
        *(uint4*)&x[8]  = *(const uint4*)(ap+8);
        *(uint4*)&x[12] = *(const uint4*)(ap+12);
        u16 hh[16];
        #pragma unroll
        for (int t=0;t<16;t++) hh[t] = (u16)(x[t]&0xffffu);
        *(short8*)&AsH[o]   = *(short8*)&hh[0];
        *(short8*)&AsH[o+8] = *(short8*)&hh[8];
        if constexpr (SPLIT == 3){
          u16 ll[16];
          #pragma unroll
          for (int t=0;t<16;t++) ll[t] = (u16)(x[t]>>16);
          *(short8*)&AsL[o]   = *(short8*)&ll[0];
          *(short8*)&AsL[o+8] = *(short8*)&ll[8];
        }
      } else {  // AFMT == 2: bf16 u16, pure copy
        const u16* ap = (const u16*)Ain + (size_t)z*zA + (size_t)(m0+sr)*lda + k0 + kc;
        *(short8*)&AsH[o]   = *(const short8*)(ap+0);
        *(short8*)&AsH[o+8] = *(const short8*)(ap+8);
      }
    }
    // ---- stage B: pure copy of pre-split weights
    if constexpr (SPLIT == 3){
      const u16* src = (sel ? WL : WH) + (size_t)(n0+sr)*ldw + k0;
      u16* dst = (sel ? BsL : BsH) + sr*40;
      #pragma unroll
      for (int c=0;c<4;c++)
        *(short8*)&dst[c*8] = *(const short8*)&src[c*8];
    } else {
      const u16* src = WH + (size_t)(n0+sr)*ldw + k0 + kc;
      u16* dst = BsH + sr*40 + kc;
      *(short8*)&dst[0] = *(const short8*)(src+0);
      *(short8*)&dst[8] = *(const short8*)(src+8);
    }
    __syncthreads();

    short8 aH[4], bH[4];
    #pragma unroll
    for (int i=0;i<4;i++) aH[i] = *(const short8*)&AsH[(wm + 16*i + r)*40 + q*8];
    #pragma unroll
    for (int j=0;j<4;j++) bH[j] = *(const short8*)&BsH[(wn + 16*j + r)*40 + q*8];
    if constexpr (SPLIT == 3){
      short8 aL[4], bL[4];
      #pragma unroll
      for (int i=0;i<4;i++) aL[i] = *(const short8*)&AsL[(wm + 16*i + r)*40 + q*8];
      #pragma unroll
      for (int j=0;j<4;j++) bL[j] = *(const short8*)&BsL[(wn + 16*j + r)*40 + q*8];
      #pragma unroll
      for (int i=0;i<4;i++)
        #pragma unroll
        for (int j=0;j<4;j++){
          acc[i][j] = __builtin_amdgcn_mfma_f32_16x16x32_bf16(aH[i], bH[j], acc[i][j], 0,0,0);
          acc[i][j] = __builtin_amdgcn_mfma_f32_16x16x32_bf16(aH[i], bL[j], acc[i][j], 0,0,0);
          acc[i][j] = __builtin_amdgcn_mfma_f32_16x16x32_bf16(aL[i], bH[j], acc[i][j], 0,0,0);
        }
    } else {
      #pragma unroll
      for (int i=0;i<4;i++)
        #pragma unroll
        for (int j=0;j<4;j++)
          acc[i][j] = __builtin_amdgcn_mfma_f32_16x16x32_bf16(aH[i], bH[j], acc[i][j], 0,0,0);
    }
    __syncthreads();
  }

  float*    Cf = (float*)Cout    + (size_t)z*zC;
  unsigned* Cp = (unsigned*)Cout + (size_t)z*zC;
  u16*      Cu = (u16*)Cout      + (size_t)z*zC;
  const float* bz = bias ? (bias + (size_t)z*zB) : bias;
  #pragma unroll
  for (int j=0;j<4;j++){
    int n_out = n0 + wn + 16*j + r;
    float bv = (bz && (!SPLITK || z==0)) ? bz[n_out] : 0.f;
    #pragma unroll
    for (int i=0;i<4;i++){
      #pragma unroll
      for (int reg=0;reg<4;reg++){
        int m_out = m0 + wm + 16*i + 4*q + reg;
        float v = acc[i][j][reg] + bv;
        if (EPI & 1) v *= sigm(v);
        size_t o = (size_t)m_out*N + n_out;
        if      (EPI & 16) atomicAdd(&Cf[o], v);
        else if (EPI & 8)  Cu[o] = bf16_rne(v);
        else if (EPI & 4)  Cp[o] = packhl(v);
        else if (EPI & 2)  Cf[o] += v;
        else               Cf[o] = v;
      }
    }
  }
}

// ---------------------------------------------------------------------------
// xproj GEMM: DBC[4096][36] = U[4096][1536] @ xw; pre-split xwT[48][1536].
// ---------------------------------------------------------------------------
__global__ __launch_bounds__(64) void xgemm_k(
    const float* __restrict__ A, const u16* __restrict__ XH,
    const u16* __restrict__ XL, float* __restrict__ DBC)
{
  int m0 = blockIdx.x*16;
  int lane = threadIdx.x;
  int r = lane&15, q = lane>>4;
  f32x4 acc[3];
  #pragma unroll
  for (int j=0;j<3;j++)
    #pragma unroll
    for (int t=0;t<4;t++) acc[j][t]=0.f;

  for (int k0 = 0; k0 < EDIM; k0 += 32){
    const float* ap = A + (size_t)(m0+r)*EDIM + k0 + q*8;
    float f[8];
    *(float4*)&f[0] = *(const float4*)(ap+0);
    *(float4*)&f[4] = *(const float4*)(ap+4);
    short8 ah, al;
    #pragma unroll
    for (int t=0;t<8;t++){
      u16 h = bf16_rne(f[t]);
      ah[t] = (short)h;
      al[t] = (short)bf16_rne(f[t]-bf16_f(h));
    }
    #pragma unroll
    for (int j=0;j<3;j++){
      size_t o = (size_t)(16*j+r)*EDIM + k0 + q*8;
      short8 bh = *(const short8*)&XH[o];
      short8 bl = *(const short8*)&XL[o];
      acc[j] = __builtin_amdgcn_mfma_f32_16x16x32_bf16(ah, bh, acc[j], 0,0,0);
      acc[j] = __builtin_amdgcn_mfma_f32_16x16x32_bf16(ah, bl, acc[j], 0,0,0);
      acc[j] = __builtin_amdgcn_mfma_f32_16x16x32_bf16(al, bh, acc[j], 0,0,0);
    }
  }
  #pragma unroll
  for (int j=0;j<3;j++){
    int n = 16*j + r;
    if (n < 36){
      #pragma unroll
      for (int reg=0;reg<4;reg++){
        int m = m0 + 4*q + reg;
        DBC[(size_t)m*36 + n] = acc[j][reg];
      }
    }
  }
}

// ---------------------------------------------------------------------------
__global__ __launch_bounds__(256) void embed_k(
    const int* __restrict__ ids, const float* __restrict__ tok,
    const float* __restrict__ pos, float* __restrict__ HS)
{
  int idx = blockIdx.x*256 + threadIdx.x;
  int h = idx % HDIM; int t = idx / HDIM;
  int lpos = t % LSEQ;
  int id = ids[t];
  HS[idx] = tok[id*HDIM + h] + pos[lpos*HDIM + h];
}

// ---------------------------------------------------------------------------
template<int PACK>
__global__ __launch_bounds__(256) void ln_k(
    const float* __restrict__ X, const float* __restrict__ w,
    const float* __restrict__ b, void* __restrict__ O)
{
  int t = blockIdx.x;
  const float* x = X + (size_t)t*HDIM;
  float s=0.f, s2=0.f;
  for (int i=threadIdx.x; i<HDIM; i+=256){ float v=x[i]; s+=v; s2+=v*v; }
  #pragma unroll
  for (int off=32; off; off>>=1){ s += __shfl_down(s,off,64); s2 += __shfl_down(s2,off,64); }
  __shared__ float rs[4], rs2[4], mv[2];
  int lane = threadIdx.x & 63, wv = threadIdx.x >> 6;
  if (!lane){ rs[wv]=s; rs2[wv]=s2; }
  __syncthreads();
  if (!threadIdx.x){
    float a = rs[0]+rs[1]+rs[2]+rs[3];
    float c = rs2[0]+rs2[1]+rs2[2]+rs2[3];
    float m = a/HDIM;
    mv[0]=m; mv[1]=rsqrtf(c/HDIM - m*m + 1e-5f);
  }
  __syncthreads();
  float m = mv[0], r = mv[1];
  for (int i=threadIdx.x; i<HDIM; i+=256){
    float v = (x[i]-m)*r*w[i] + b[i];
    if (PACK) ((unsigned*)O)[(size_t)t*HDIM+i] = packhl(v);
    else      ((float*)O)[(size_t)t*HDIM+i] = v;
  }
}

// ---------------------------------------------------------------------------
__global__ __launch_bounds__(256) void conv_silu_k(
    const float* __restrict__ PROJ, const float* __restrict__ cw,
    const float* __restrict__ cb, float* __restrict__ U)
{
  int idx = blockIdx.x*256 + threadIdx.x;
  int e = idx % EDIM; int t = idx / EDIM;
  int l = t % LSEQ; int tb = t - l;
  float acc = cb[e];
  #pragma unroll
  for (int j=0;j<4;j++){
    int tt = l + j - 3;
    if (tt >= 0) acc += PROJ[(size_t)(tb+tt)*(2*EDIM) + e] * cw[e*4+j];
  }
  U[idx] = acc * sigm(acc);
}

// ---------------------------------------------------------------------------
// Coalesced chunked scan (round 6): thread = (channel, chunk), 16 states in
// registers; lanes = consecutive channels.
// ---------------------------------------------------------------------------
__global__ __launch_bounds__(256) void scanA_k(
    const float* __restrict__ U, const float* __restrict__ DBC,
    const float* __restrict__ Alog, const float* __restrict__ dtw,
    const float* __restrict__ dtb, float* __restrict__ PSP,
    float* __restrict__ PSS)
{
  const int CH = LSEQ/NCHK;
  int el = threadIdx.x & 63, jj = threadIdx.x >> 6;
  int ch = blockIdx.x*64 + el;
  int j  = blockIdx.y*4 + jj;
  int e = ch % EDIM, b = ch / EDIM;

  float a[16], P[16], S[16];
  #pragma unroll
  for (int n=0;n<16;n++){ a[n] = -__expf(Alog[e*NST+n]); P[n]=1.f; S[n]=0.f; }
  float w0=dtw[e], w1=dtw[EDIM+e], w2=dtw[2*EDIM+e], w3=dtw[3*EDIM+e];
  float db=dtb[e];
  size_t base=(size_t)b*LSEQ;

  for (int t=j*CH; t<j*CH+CH; t++){
    size_t tok = base+t;
    float4 d4 = *(const float4*)&DBC[tok*36];
    float4 B0 = *(const float4*)&DBC[tok*36+4];
    float4 B1 = *(const float4*)&DBC[tok*36+8];
    float4 B2 = *(const float4*)&DBC[tok*36+12];
    float4 B3 = *(const float4*)&DBC[tok*36+16];
    float dt = d4.x*w0 + d4.y*w1 + d4.z*w2 + d4.w*w3 + db;
    dt = (dt>20.f)?dt:log1pf(__expf(dt));
    float du = dt * U[tok*EDIM+e];
    float Bv[16];
    *(float4*)&Bv[0]=B0; *(float4*)&Bv[4]=B1; *(float4*)&Bv[8]=B2; *(float4*)&Bv[12]=B3;
    #pragma unroll
    for (int n=0;n<16;n++){
      float dA = __expf(dt*a[n]);
      P[n]*=dA; S[n]=S[n]*dA + du*Bv[n];
    }
  }
  #pragma unroll
  for (int n=0;n<16;n++){
    PSP[(size_t)(j*16+n)*NCH + ch] = P[n];
    PSS[(size_t)(j*16+n)*NCH + ch] = S[n];
  }
}

__global__ __launch_bounds__(256) void scanB_k(
    const float* __restrict__ PSP, const float* __restrict__ PSS,
    float* __restrict__ HIN)
{
  int idx = blockIdx.x*256 + threadIdx.x;   // over NCH*16
  int n = idx / NCH, ch = idx % NCH;
  float hin = 0.f;
  #pragma unroll
  for (int jj=0;jj<NCHK;jj++){
    size_t o = (size_t)(jj*16+n)*NCH + ch;
    HIN[o] = hin;
    hin = PSP[o]*hin + PSS[o];
  }
}

__global__ __launch_bounds__(256) void scanC_k(
    const float* __restrict__ U, const float* __restrict__ DBC,
    const float* __restrict__ Alog, const float* __restrict__ dtw,
    const float* __restrict__ dtb, const float* __restrict__ HIN,
    const float* __restrict__ Dp, float* __restrict__ PROJ)
{
  const int CH = LSEQ/NCHK;
  int el = threadIdx.x & 63, jj = threadIdx.x >> 6;
  int ch = blockIdx.x*64 + el;
  int j  = blockIdx.y*4 + jj;
  int e = ch % EDIM, b = ch / EDIM;

  float a[16], h[16];
  #pragma unroll
  for (int n=0;n<16;n++){
    a[n] = -__expf(Alog[e*NST+n]);
    h[n] = HIN[(size_t)(j*16+n)*NCH + ch];
  }
  float w0=dtw[e], w1=dtw[EDIM+e], w2=dtw[2*EDIM+e], w3=dtw[3*EDIM+e];
  float db=dtb[e], dcf=Dp[e];
  size_t base=(size_t)b*LSEQ;
  unsigned* Yp = (unsigned*)PROJ;

  for (int t=j*CH; t<j*CH+CH; t++){
    size_t tok = base+t;
    float4 d4 = *(const float4*)&DBC[tok*36];
    float4 B0 = *(const float4*)&DBC[tok*36+4];
    float4 B1 = *(const float4*)&DBC[tok*36+8];
    float4 B2 = *(const float4*)&DBC[tok*36+12];
    float4 B3 = *(const float4*)&DBC[tok*36+16];
    float4 C0 = *(const float4*)&DBC[tok*36+20];
    float4 C1 = *(const float4*)&DBC[tok*36+24];
    float4 C2 = *(const float4*)&DBC[tok*36+28];
    float4 C3 = *(const float4*)&DBC[tok*36+32];
    float dt = d4.x*w0 + d4.y*w1 + d4.z*w2 + d4.w*w3 + db;
    dt = (dt>20.f)?dt:log1pf(__expf(dt));
    float u = U[tok*EDIM+e];
    float du = dt * u;
    float Bv[16], Cv[16];
    *(float4*)&Bv[0]=B0; *(float4*)&Bv[4]=B1; *(float4*)&Bv[8]=B2; *(float4*)&Bv[12]=B3;
    *(float4*)&Cv[0]=C0; *(float4*)&Cv[4]=C1; *(float4*)&Cv[8]=C2; *(float4*)&Cv[12]=C3;
    float y = 0.f;
    #pragma unroll
    for (int n=0;n<16;n++){
      float dA = __expf(dt*a[n]);
      h[n] = h[n]*dA + du*Bv[n];
      y += h[n]*Cv[n];
    }
    float g = PROJ[tok*(2*EDIM) + EDIM + e];
    Yp[tok*(2*EDIM) + e] = packhl((y + u*dcf)*sigm(g));
  }
}

// HS += (FB0 + FB1 + FB2)/6
__global__ __launch_bounds__(256) void addscale3_k(
    float* __restrict__ HS, const float* __restrict__ FB)
{
  const size_t S = (size_t)BLTOK*HDIM;
  size_t i = blockIdx.x*256 + threadIdx.x;
  HS[i] += (FB[i] + FB[i+S] + FB[i+2*S]) * (0.5f/3.0f);
}

// ---------------------------------------------------------------------------
extern "C" void kernel_launch(void* const* d_in, const int* in_sizes, int n_in,
                              void* d_out, int out_size, void* d_ws, size_t ws_size,
                              hipStream_t stream)
{
  const int*   ids      = (const int*)d_in[0];
  const float* tok_emb  = (const float*)d_in[1];
  const float* pos_emb  = (const float*)d_in[2];
  const float* ln_w     = (const float*)d_in[3];
  const float* ln_b     = (const float*)d_in[4];
  const float* in_w     = (const float*)d_in[5];
  const float* in_b     = (const float*)d_in[6];
  const float* conv_w   = (const float*)d_in[7];
  const float* conv_b   = (const float*)d_in[8];
  const float* xproj_w  = (const float*)d_in[9];
  const float* dt_w     = (const float*)d_in[10];
  const float* dt_b     = (const float*)d_in[11];
  const float* A_log    = (const float*)d_in[12];
  const float* Dp       = (const float*)d_in[13];
  const float* out_w    = (const float*)d_in[14];
  const float* out_b    = (const float*)d_in[15];
  const float* frac_w   = (const float*)d_in[16];
  const float* frac_b   = (const float*)d_in[17];
  const float* fln_w    = (const float*)d_in[18];
  const float* fln_b    = (const float*)d_in[19];

  // ---- workspace map
  const size_t F_HS   = (size_t)BLTOK*HDIM;      // 3,145,728 floats
  const size_t F_PROJ = (size_t)BLTOK*2*EDIM;    // 12,582,912
  const size_t F_R1   = (size_t)BLTOK*EDIM;      //  6,291,456
  float* HS   = (float*)d_ws;
  float* PROJ = HS   + F_HS;
  float* R1   = PROJ + F_PROJ;                   // XBp, then U
  float* DBC  = R1   + F_R1;
  u16* W16  = (u16*)(DBC + (size_t)BLTOK*36);
  u16* inH  = W16;
  u16* inL  = inH  + (size_t)2359296;
  u16* outH = inL  + (size_t)2359296;
  u16* outL = outH + (size_t)1179648;
  u16* frH  = outL + (size_t)1179648;
  u16* frL  = frH  + (size_t)1769472;
  u16* xH   = frL  + (size_t)1769472;
  u16* xL   = xH   + (size_t)73728;
  float* PSP = (float*)(xL + (size_t)73728);
  float* PSS = PSP + (size_t)786432;
  float* HIN = PSS + (size_t)786432;
  // aliases (PROJ+R1 region = 6*F_HS floats total, dead after out-proj)
  unsigned* XBp = (unsigned*)R1;                 // packed LN out
  float*    U   = R1;                            // fp32 conv out
  float*    FB  = PROJ;                          // fractal stage3 out, 3*F_HS f32
  u16*      S1  = (u16*)(PROJ + 3*F_HS);         // stage1 out, 3*F_HS u16
  u16*      S2  = S1 + 3*F_HS;                   // stage2 out, 3*F_HS u16

  embed_k<<<(BLTOK*HDIM)/256, 256, 0, stream>>>(ids, tok_emb, pos_emb, HS);

  const size_t zWf = (size_t)HDIM*HDIM;
  for (int l = 0; l < NLAYER; l++){
    wprep_k<<<dim3(3072/32, 768/32), 256, 0, stream>>>(
        in_w + (size_t)l*HDIM*2*EDIM, inH, inL, 2*EDIM, 2*EDIM, HDIM);
    wprep_k<<<dim3(768/32, 1536/32), 256, 0, stream>>>(
        out_w + (size_t)l*EDIM*HDIM, outH, outL, HDIM, HDIM, EDIM);
    wprep_k<<<dim3(768/32, 768/32, 3), 256, 0, stream>>>(
        frac_w + (size_t)l*3*HDIM*HDIM, frH, frL, HDIM, HDIM, HDIM);
    wprep_k<<<dim3(2, 1536/32), 256, 0, stream>>>(
        xproj_w + (size_t)l*EDIM*36, xH, xL, 36, 48, EDIM);

    // LN -> packed
    ln_k<1><<<BLTOK, 256, 0, stream>>>(HS, ln_w + l*HDIM, ln_b + l*HDIM, XBp);

    // proj = LN(hs) @ in_w + in_b   [4096 x 768 -> 3072], bf16x3
    gemm_u<0,1,3,0><<<dim3(24, 32), 256, 0, stream>>>(
        XBp, HDIM, inH, inL, HDIM, in_b + l*2*EDIM, PROJ,
        2*EDIM, HDIM, 0,0,0,0);

    conv_silu_k<<<(BLTOK*EDIM)/256, 256, 0, stream>>>(
        PROJ, conv_w + l*EDIM*4, conv_b + l*EDIM, U);

    // dbc = u @ xproj_w
    xgemm_k<<<BLTOK/16, 64, 0, stream>>>(U, xH, xL, DBC);

    // selective scan (coalesced 3-phase), packed Y into PROJ[:, :E]
    scanA_k<<<dim3(NCH/64, 4), 256, 0, stream>>>(
        U, DBC, A_log + (size_t)l*EDIM*NST, dt_w + (size_t)l*4*EDIM,
        dt_b + (size_t)l*EDIM, PSP, PSS);
    scanB_k<<<(NCH*16)/256, 256, 0, stream>>>(PSP, PSS, HIN);
    scanC_k<<<dim3(NCH/64, 4), 256, 0, stream>>>(
        U, DBC, A_log + (size_t)l*EDIM*NST, dt_w + (size_t)l*4*EDIM,
        dt_b + (size_t)l*EDIM, HIN, Dp + (size_t)l*EDIM, PROJ);

    // hs += y @ out_w + out_b  [4096 x 1536 -> 768], bf16x3, split-K=2, atomic
    gemm_u<16,1,3,1><<<dim3(6, 32, 2), 256, 0, stream>>>(
        (unsigned*)PROJ, 2*EDIM, outH, outL, EDIM, out_b + l*HDIM, HS,
        HDIM, EDIM/2, /*zA*/EDIM/2, /*zW*/EDIM/2, 0, 0);

    // fractal: plain bf16 (error attenuated /6), 3 z-batched stages
    gemm_u<9,0,1,0><<<dim3(6, 32, 3), 256, 0, stream>>>(
        HS, HDIM, frH, frL, HDIM, frac_b + (size_t)l*3*HDIM, S1,
        HDIM, HDIM, 0, zWf, HDIM, F_HS);
    gemm_u<9,2,1,0><<<dim3(6, 32, 3), 256, 0, stream>>>(
        S1, HDIM, frH, frL, HDIM, frac_b + (size_t)l*3*HDIM, S2,
        HDIM, HDIM, F_HS, zWf, HDIM, F_HS);
    gemm_u<1,2,1,0><<<dim3(6, 32, 3), 256, 0, stream>>>(
        S2, HDIM, frH, frL, HDIM, frac_b + (size_t)l*3*HDIM, FB,
        HDIM, HDIM, F_HS, zWf, HDIM, F_HS);

    addscale3_k<<<(BLTOK*HDIM)/256, 256, 0, stream>>>(HS, FB);
  }

  ln_k<0><<<BLTOK, 256, 0, stream>>>(HS, fln_w, fln_b, (float*)d_out);
}